// Round 19
// baseline (1644.950 us; speedup 1.0000x reference)
//
#include <hip/hip_runtime.h>

typedef _Float16 half8 __attribute__((ext_vector_type(8)));
typedef _Float16 half2v __attribute__((ext_vector_type(2)));
typedef float floatx16 __attribute__((ext_vector_type(16)));

static constexpr int gT = 256;      // time steps
static constexpr int gV = 24;       // graph nodes
static constexpr int gN = gT * gV;  // 6144 columns per batch
static constexpr float BN_INV = 0.99999500003749969f; // 1/sqrt(1+1e-5)

#define GLOAD_LDS16(g, l)                                            \
  __builtin_amdgcn_global_load_lds(                                  \
      (const __attribute__((address_space(1))) unsigned int*)(g),    \
      (__attribute__((address_space(3))) unsigned int*)(l), 16, 0, 0)

// ============================= prep kernels =============================
__global__ __launch_bounds__(256) void k_prep_aeff(
    const float* __restrict__ A, const float* __restrict__ e0,
    const float* __restrict__ e1, const float* __restrict__ e2,
    float* __restrict__ aeff, float* __restrict__ csum)
{
  int tid = blockIdx.x * 256 + threadIdx.x;
  if (tid < 3 * 1728) {
    int l = tid / 1728, r = tid % 1728;
    const float* e = (l == 0) ? e0 : ((l == 1) ? e1 : e2);
    aeff[tid] = A[r] * e[r];
  }
  if (tid < 3 * 72) {
    int l = tid / 72, r = tid % 72;
    int k = r / 24, w = r % 24;
    const float* e = (l == 0) ? e0 : ((l == 1) ? e1 : e2);
    float s = 0.f;
    for (int v = 0; v < 24; ++v) { int idx = (k * 24 + v) * 24 + w; s += A[idx] * e[idx]; }
    csum[tid] = s;
  }
}

// Pack tcn weights into MFMA A-fragment order, f16 hi/lo split.
__global__ __launch_bounds__(256) void k_prep_twf(
    const float* __restrict__ tw, _Float16* __restrict__ out, int CI, int KT)
{
  int g = blockIdx.x * 256 + threadIdx.x;
  int fid = g >> 6, lane = g & 63;
  int pl = fid & 1;
  int f2 = fid >> 1;
  int dt = f2 % 5;
  int f3 = f2 / 5;
  int ks = f3 & 1;
  int f4 = f3 >> 1;
  int kt = f4 % KT;
  int mt = f4 / KT;
  int m = mt * 32 + (lane & 31);
  int kb = kt * 32 + ks * 16 + ((lane >> 5) << 3);
  half8 o;
#pragma unroll
  for (int e = 0; e < 8; ++e) {
    float v = tw[((size_t)m * CI + (kb + e)) * 5 + dt];
    _Float16 h = (_Float16)v;
    o[e] = pl ? (_Float16)(v - (float)h) : h;
  }
  *(half8*)(out + ((size_t)fid * 64 + lane) * 8) = o;
}

// Pack gcn W_big = [Wg(3*COUT rows); Wr(COUT rows)] into fuse A-fragments.
__global__ __launch_bounds__(256) void k_pack_wz(
    const float* __restrict__ Wg, const float* __restrict__ Wr,
    _Float16* __restrict__ out, int CIN, int KT, int M3)
{
  int g = blockIdx.x * 256 + threadIdx.x;
  int fid = g >> 6, lane = g & 63;
  int pl = fid & 1;
  int ks = (fid >> 1) & 1;
  int rest = fid >> 2;
  int kt = rest % KT;
  int mt = rest / KT;
  int m = mt * 32 + (lane & 31);
  int kb = kt * 32 + ks * 16 + ((lane >> 5) << 3);
  const float* row = (m < M3) ? (Wg + (size_t)m * CIN) : (Wr + (size_t)(m - M3) * CIN);
  half8 o;
#pragma unroll
  for (int e = 0; e < 8; ++e) {
    float v = row[kb + e];
    _Float16 h = (_Float16)v;
    o[e] = pl ? (_Float16)(v - (float)h) : h;
  }
  *(half8*)(out + ((size_t)fid * 64 + lane) * 8) = o;
}

// ============================= layer 0 GCN (4 t per block) =============================
__global__ __launch_bounds__(256) void k_gcn0(
    const float* __restrict__ x,      // [B][T][24][3]
    const float* __restrict__ aeff,   // [3][24][24]
    const float* __restrict__ csum,   // [3][24]
    const float* __restrict__ dbg, const float* __restrict__ dbb,  // [72]
    const float* __restrict__ W0,     // [768][3]
    const float* __restrict__ gb0,    // [768]
    const float* __restrict__ g1, const float* __restrict__ b1,    // [256]
    _Float16* __restrict__ yh, _Float16* __restrict__ yl,          // [NBc][256]
    int b0)
{
  __shared__ float xbn[72];      // [cin][v]
  __shared__ float XA[216];      // [(k*3+ci)][w]
  __shared__ float WL[2304];
  __shared__ float tile[256 * 25];
  int t0 = blockIdx.x * 4, bl = blockIdx.y, tid = threadIdx.x;
  int b = b0 + bl;
  int c = tid;

  for (int i = tid; i < 2304; i += 256) WL[i] = W0[i];

  for (int tr = 0; tr < 4; ++tr) {
    int t = t0 + tr;
    __syncthreads();                 // WL ready (tr=0); xbn/tile free (tr>0)
    if (tid < 72) {
      int v = tid / 3, cin = tid % 3;
      float xv = x[(((size_t)b * gT + t) * gV + v) * 3 + cin];
      xbn[cin * 24 + v] = xv * (BN_INV * dbg[tid]) + dbb[tid];
    }
    __syncthreads();
    if (tid < 216) {
      int k = tid / 72, r = tid % 72, ci = r / 24, w = r % 24;
      const float* Ak = aeff + k * 576;
      float s = 0.f;
#pragma unroll
      for (int v = 0; v < 24; ++v) s += xbn[ci * 24 + v] * Ak[v * 24 + w];
      XA[tid] = s;
    }
    __syncthreads();

    float acc[24];
#pragma unroll
    for (int w = 0; w < 24; ++w) acc[w] = 0.f;
#pragma unroll
    for (int k = 0; k < 3; ++k) {
#pragma unroll
      for (int ci = 0; ci < 3; ++ci) {
        float wv = WL[(k * 256 + c) * 3 + ci];
#pragma unroll
        for (int w = 0; w < 24; ++w) acc[w] += wv * XA[(k * 3 + ci) * 24 + w];
      }
      float gv = gb0[k * 256 + c];
#pragma unroll
      for (int w = 0; w < 24; ++w) acc[w] += gv * csum[k * 24 + w];
    }
    float s1 = BN_INV * g1[c], o1 = b1[c];
#pragma unroll
    for (int w = 0; w < 24; ++w) tile[c * 25 + w] = fmaxf(acc[w] * s1 + o1, 0.f);
    __syncthreads();

    // vectorized plane writes: 8 c per thread, half8 (16B) stores; slab contiguous.
    size_t nb = ((size_t)bl * gN + (size_t)t * 24);
    _Float16* dhB = yh + nb * 256;
    _Float16* dlB = yl + nb * 256;
#pragma unroll
    for (int it = 0; it < 3; ++it) {
      int idx = it * 256 + tid;          // < 768 = 24 w * 32 c-octets
      int w = idx >> 5;
      int c0 = (idx & 31) * 8;
      half8 vh, vl;
#pragma unroll
      for (int q = 0; q < 8; ++q) {
        float v = tile[(c0 + q) * 25 + w];
        _Float16 hh = (_Float16)v;
        vh[q] = hh;
        vl[q] = (_Float16)(v - (float)hh);
      }
      *(half8*)(dhB + (size_t)w * 256 + c0) = vh;
      *(half8*)(dlB + (size_t)w * 256 + c0) = vl;
    }
  }
}

// ============================= fused gcn: Z-GEMM + A-contraction =============================
template <int CIN, int COUT>
__global__ __launch_bounds__(512) void k_gcnfuse(
    const _Float16* __restrict__ pH, const _Float16* __restrict__ pL, // [NBc][CIN]
    const _Float16* __restrict__ Wf,
    const float* __restrict__ aeffL, const float* __restrict__ csumL,
    const float* __restrict__ gb, const float* __restrict__ g1, const float* __restrict__ b1,
    _Float16* __restrict__ oH, _Float16* __restrict__ oL,  // [NBc][COUT]
    float* __restrict__ res_out,                           // [COUT][NBc] raw Z res rows
    int NBc)
{
  constexpr int KT = CIN / 32;
  constexpr int M = 4 * COUT;
  constexpr int M3 = 3 * COUT;
  constexpr int MT = M / 256;           // mt-tiles per wave (8 waves): L1: 2, L2: 1
  constexpr int BSTG_FL = 2 * 2 * 96 * 40 / 2;  // dbuf B staging, in floats (7680)
  constexpr int ZLW = M * 25;                   // ZL floats (L1: 12800, L2: 6400)
  constexpr int UNIW = (ZLW > BSTG_FL) ? ZLW : BSTG_FL;
  __shared__ float UNI[UNIW];
  __shared__ float AL[1728];
  __shared__ float csL[72];
  __shared__ __align__(16) _Float16 YST[24 * COUT * 2];  // staged y slab: hi | lo planes
  _Float16* Bb = (_Float16*)UNI;
  float* ZL = UNI;

  int tid = threadIdx.x, w = tid >> 6, lane = tid & 63;
  int n0 = blockIdx.x * 96;

  for (int i = tid; i < 1728; i += 512) AL[i] = aeffL[i];
  if (tid < 72) csL[tid] = csumL[tid];

  floatx16 acc[MT][3] = {};

  uint4 pf[2];
  auto PREF = [&](int kt) {
#pragma unroll
    for (int it = 0; it < 2; ++it) {
      int task = it * 512 + tid;       // 768 = 96 rows * 2 planes * 4 segs
      if (task < 768) {
        int row = task >> 3, pl = (task >> 2) & 1, seg = task & 3;
        pf[it] = *(const uint4*)((pl ? pL : pH) + (size_t)(n0 + row) * CIN + kt * 32 + seg * 8);
      }
    }
  };
  auto WRITE = [&](int buf) {
#pragma unroll
    for (int it = 0; it < 2; ++it) {
      int task = it * 512 + tid;
      if (task < 768) {
        int row = task >> 3, pl = (task >> 2) & 1, seg = task & 3;
        *(uint4*)(Bb + (((size_t)buf * 2 + pl) * 96 + row) * 40 + seg * 8) = pf[it];
      }
    }
  };

  PREF(0); WRITE(0); __syncthreads();
  int cur = 0;
  for (int kt = 0; kt < KT; ++kt) {
    if (kt + 1 < KT) PREF(kt + 1);     // loads fly during MFMA below
    const _Float16* BH = Bb + (size_t)(cur * 2 + 0) * 96 * 40;
    const _Float16* BL2 = Bb + (size_t)(cur * 2 + 1) * 96 * 40;
    __builtin_amdgcn_s_setprio(1);
#pragma unroll
    for (int ks = 0; ks < 2; ++ks) {
      int koff = ks * 16 + ((lane >> 5) << 3);
      int rowb = lane & 31;
      half8 bh[3], bl[3];
#pragma unroll
      for (int nf = 0; nf < 3; ++nf) {
        bh[nf] = *(const half8*)(BH + (rowb + nf * 32) * 40 + koff);
        bl[nf] = *(const half8*)(BL2 + (rowb + nf * 32) * 40 + koff);
      }
#pragma unroll
      for (int mti = 0; mti < MT; ++mti) {
        int mt = w * MT + mti;
        int fid = ((mt * KT + kt) * 2 + ks) * 2;
        half8 ah = *(const half8*)(Wf + ((size_t)fid * 64 + lane) * 8);
        half8 al = *(const half8*)(Wf + ((size_t)(fid + 1) * 64 + lane) * 8);
#pragma unroll
        for (int nf = 0; nf < 3; ++nf) {
          acc[mti][nf] = __builtin_amdgcn_mfma_f32_32x32x16_f16(ah, bh[nf], acc[mti][nf], 0, 0, 0);
          acc[mti][nf] = __builtin_amdgcn_mfma_f32_32x32x16_f16(ah, bl[nf], acc[mti][nf], 0, 0, 0);
          acc[mti][nf] = __builtin_amdgcn_mfma_f32_32x32x16_f16(al, bh[nf], acc[mti][nf], 0, 0, 0);
        }
      }
    }
    __builtin_amdgcn_s_setprio(0);
    if (kt + 1 < KT) WRITE(cur ^ 1);   // vmcnt wait lands here, after MFMA
    __syncthreads();
    cur ^= 1;
  }

  constexpr int SUBS = 512 / COUT;     // L1: 4, L2: 8
  constexpr int WR = 24 / SUBS;        // L1: 6, L2: 3
  int c = tid & (COUT - 1);
  int w0 = (tid / COUT) * WR;
  float s1 = BN_INV * g1[c], o1 = b1[c];
  float gv0 = gb[c], gv1 = gb[COUT + c], gv2 = gb[2 * COUT + c];

  for (int tr = 0; tr < 4; ++tr) {
    __syncthreads();
#pragma unroll
    for (int mti = 0; mti < MT; ++mti) {
#pragma unroll
      for (int nf = 0; nf < 3; ++nf) {
        int nloc = nf * 32 + (lane & 31) - tr * 24;
        if (nloc >= 0 && nloc < 24) {
          int mb_ = (w * MT + mti) * 32 + 4 * (lane >> 5);
#pragma unroll
          for (int r = 0; r < 16; ++r)
            ZL[(mb_ + (r & 3) + 8 * (r >> 2)) * 25 + nloc] = acc[mti][nf][r];
        }
      }
    }
    __syncthreads();
    float y[WR];
#pragma unroll
    for (int j = 0; j < WR; ++j) y[j] = 0.f;
#pragma unroll
    for (int k = 0; k < 3; ++k) {
#pragma unroll
      for (int v = 0; v < 24; ++v) {
        float zr = ZL[(k * COUT + c) * 25 + v];
        const float* ap = &AL[k * 576 + v * 24 + w0];
#pragma unroll
        for (int j = 0; j < WR; ++j) y[j] += zr * ap[j];
      }
    }
#pragma unroll
    for (int j = 0; j < WR; ++j) {
      int ww = w0 + j;
      float bias = gv0 * csL[ww] + gv1 * csL[24 + ww] + gv2 * csL[48 + ww];
      float yv = fmaxf((y[j] + bias) * s1 + o1, 0.f);
      _Float16 h = (_Float16)yv;
      YST[ww * COUT + c] = h;
      YST[24 * COUT + ww * COUT + c] = (_Float16)(yv - (float)h);
    }
    __syncthreads();
    // bulk 16B plane writes (slab contiguous in global) + float4 res writes
    constexpr int QT = 24 * COUT / 8;        // half8 per plane
    size_t nbase = (size_t)n0 + tr * 24;
    for (int idx = tid; idx < 2 * QT; idx += 512) {
      int plane = idx / QT, q = idx - plane * QT;
      _Float16* dst = (plane ? oL : oH) + nbase * COUT + q * 8;
      *(half8*)dst = *(half8*)(YST + plane * 24 * COUT + q * 8);
    }
    for (int idx = tid; idx < COUT * 6; idx += 512) {
      int cc = idx / 6, q = idx - cc * 6;
      float4 v4;
      v4.x = ZL[(M3 + cc) * 25 + 4 * q + 0];
      v4.y = ZL[(M3 + cc) * 25 + 4 * q + 1];
      v4.z = ZL[(M3 + cc) * 25 + 4 * q + 2];
      v4.w = ZL[(M3 + cc) * 25 + 4 * q + 3];
      *(float4*)(res_out + (size_t)cc * NBc + nbase + 4 * q) = v4;
    }
  }
}

// ============================= temporal conv (MFMA, 512 thr, N_BLK=256, single-buf) ==========
// Halo overhead 352/256 = 1.375x (was 1.75x).  LDS ~50KB -> 3 blocks/CU = 24 waves.
// FUSE_FC: apply fc to post-relu h in-register, reduce, write d_out directly.
template <int CIO, int MF, bool FUSE_FC>
__global__ __launch_bounds__(512) void k_tcn_mfma(
    const _Float16* __restrict__ yH, const _Float16* __restrict__ yL, // [NBc][CIO]
    const _Float16* __restrict__ Apack,
    const float* __restrict__ tb, const float* __restrict__ g2, const float* __restrict__ b2,
    const float* __restrict__ Zres,   // res rows [CIO][NBc] raw, or nullptr
    const float* __restrict__ rb, const float* __restrict__ rg, const float* __restrict__ rbb,
    _Float16* __restrict__ oH, _Float16* __restrict__ oL,  // [NBc][CIO] (unused if FUSE_FC)
    const float* __restrict__ fw, const float* __restrict__ fb,  // fc params (FUSE_FC)
    float* __restrict__ outp, int b0,
    int NBc)
{
  constexpr int KT = CIO / 32;
  constexpr int M = CIO;
  constexpr int N_BLK = 256;
  constexpr int NWAVE_M = M / (MF * 32);      // 256:4  128:2  64:2
  constexpr int NWAVE_N = 8 / NWAVE_M;        // 256:2  128:4  64:4
  constexpr int NF = N_BLK / (32 * NWAVE_N);  // 256:4  128:2  64:2
  constexpr int NROW = 352;                   // 256 cols + 96 halo rows
  constexpr int NSLOT = NROW * 8;             // 16B slots (2816)
  __shared__ _Float16 Bt[NROW * 64];          // 45056 B
  __shared__ float scL[CIO], ofL[CIO], tbL[CIO], rscL[CIO], rofL[CIO], rbvL[CIO];
  __shared__ float fwL[FUSE_FC ? 384 : 4];
  int bx = blockIdx.x, bl = blockIdx.z;
  int tid = threadIdx.x, w = tid >> 6, lane = tid & 63;
  int wn = w % NWAVE_N, wm = w / NWAVE_N;
  int n0 = bx * N_BLK;
  bool interior = (bx > 0) && (bx < (gN / N_BLK - 1));

  for (int i = tid; i < CIO; i += 512) {
    scL[i] = BN_INV * g2[i]; ofL[i] = b2[i]; tbL[i] = tb[i];
    if (Zres) { rscL[i] = BN_INV * rg[i]; rofL[i] = rbb[i]; rbvL[i] = rb[i]; }
  }
  if (FUSE_FC) { for (int i = tid; i < 384; i += 512) fwL[i] = fw[i]; }

  floatx16 acc[MF][NF] = {};
  const _Float16* ybH = yH + (size_t)bl * gN * CIO;
  const _Float16* ybL = yL + (size_t)bl * gN * CIO;
  int mt_base = wm * MF;

  auto ISSUE = [&](int kt) {   // async gload_lds; 2816 slots, wave-uniform bases
#pragma unroll
    for (int it = 0; it < 6; ++it) {
      int base = it * 512 + w * 64;
      if (base < NSLOT) {
        int T = base + lane;
        int r = T >> 3, s = T & 7;
        int sl = s ^ (r & 7);
        int pl = sl >> 2, seg = sl & 3;
        int n = n0 - 48 + r;
        const _Float16* src = (pl ? ybL : ybH) + (size_t)n * CIO + kt * 32 + seg * 8;
        GLOAD_LDS16(src, Bt + (size_t)base * 8);
      }
    }
  };
  auto ISSUE_EDGE = [&](int kt) {  // reg-staged, zero-filled halo
#pragma unroll
    for (int it = 0; it < 6; ++it) {
      int T = it * 512 + tid;
      if (T < NSLOT) {
        int r = T >> 3, s = T & 7;
        int sl = s ^ (r & 7);
        int pl = sl >> 2, seg = sl & 3;
        int n = n0 - 48 + r;
        uint4 vv = make_uint4(0u, 0u, 0u, 0u);
        if (n >= 0 && n < gN)
          vv = *(const uint4*)((pl ? ybL : ybH) + (size_t)n * CIO + kt * 32 + seg * 8);
        *(uint4*)(Bt + (size_t)T * 8) = vv;
      }
    }
  };
  auto COMPUTE = [&](int kt) {
    const _Float16* B = &Bt[0];
    __builtin_amdgcn_s_setprio(1);
#pragma unroll
    for (int dt = 0; dt < 5; ++dt) {
#pragma unroll
      for (int ks = 0; ks < 2; ++ks) {
        int seg = ks * 2 + (lane >> 5);
        half8 bh[NF], blv[NF];
#pragma unroll
        for (int nf = 0; nf < NF; ++nf) {
          int rr = wn * (NF * 32) + nf * 32 + dt * 24 + (lane & 31);
          bh[nf]  = *(const half8*)(B + rr * 64 + (((0 + seg) ^ (rr & 7)) * 8));
          blv[nf] = *(const half8*)(B + rr * 64 + (((4 + seg) ^ (rr & 7)) * 8));
        }
#pragma unroll
        for (int mf = 0; mf < MF; ++mf) {
          int fid = ((((mt_base + mf) * KT + kt) * 2 + ks) * 5 + dt) * 2;
          half8 ah = *(const half8*)(Apack + ((size_t)fid * 64 + lane) * 8);
          half8 al = *(const half8*)(Apack + ((size_t)(fid + 1) * 64 + lane) * 8);
#pragma unroll
          for (int nf = 0; nf < NF; ++nf) {
            acc[mf][nf] = __builtin_amdgcn_mfma_f32_32x32x16_f16(ah, bh[nf], acc[mf][nf], 0, 0, 0);
            acc[mf][nf] = __builtin_amdgcn_mfma_f32_32x32x16_f16(ah, blv[nf], acc[mf][nf], 0, 0, 0);
            acc[mf][nf] = __builtin_amdgcn_mfma_f32_32x32x16_f16(al, bh[nf], acc[mf][nf], 0, 0, 0);
          }
        }
      }
    }
    __builtin_amdgcn_s_setprio(0);
  };

  for (int kt = 0; kt < KT; ++kt) {
    __syncthreads();                   // prior reads of Bt done
    if (interior) ISSUE(kt); else ISSUE_EDGE(kt);
    __syncthreads();                   // staging complete (vmcnt drained by compiler)
    COMPUTE(kt);
  }

  // epilogue: acc -> z (bias + bn2 + res + relu), in place
  int blgN = bl * gN;
#pragma unroll
  for (int mf = 0; mf < MF; ++mf) {
    int m32 = wm * MF * 32 + mf * 32 + 4 * (lane >> 5);
#pragma unroll
    for (int nf = 0; nf < NF; ++nf) {
      int n = n0 + wn * (NF * 32) + nf * 32 + (lane & 31);
      size_t nflat = (size_t)blgN + n;
#pragma unroll
      for (int r = 0; r < 16; ++r) {
        int co = m32 + (r & 3) + 8 * (r >> 2);
        float z = (acc[mf][nf][r] + tbL[co]) * scL[co] + ofL[co];
        if (Zres) z += (Zres[(size_t)co * NBc + nflat] + rbvL[co]) * rscL[co] + rofL[co];
        acc[mf][nf][r] = fmaxf(z, 0.f);
      }
    }
  }

  if constexpr (FUSE_FC) {
    // CIO=64: MF=1, NWAVE_M=2 (wm 0..1), NWAVE_N=4 (wn 0..3), NF=2.
    __syncthreads();                   // Bt free
    float* FC = (float*)&Bt[0];        // [2 wm][256 n][6] = 12KB
    int m32 = wm * 32 + 4 * (lane >> 5);
#pragma unroll
    for (int nf = 0; nf < 2; ++nf) {
      float p[6];
#pragma unroll
      for (int o = 0; o < 6; ++o) p[o] = 0.f;
#pragma unroll
      for (int r = 0; r < 16; ++r) {
        int co = m32 + (r & 3) + 8 * (r >> 2);
        float z = acc[0][nf][r];
#pragma unroll
        for (int o = 0; o < 6; ++o) p[o] += fwL[o * 64 + co] * z;
      }
#pragma unroll
      for (int o = 0; o < 6; ++o) p[o] += __shfl_xor(p[o], 32);
      if (lane < 32) {
        int nloc = wn * 64 + nf * 32 + lane;
#pragma unroll
        for (int o = 0; o < 6; ++o)
          FC[(wm * 256 + nloc) * 6 + o] = p[o];
      }
    }
    __syncthreads();
    for (int idx = tid; idx < 1536; idx += 512) {
      int nloc = idx / 6, o = idx % 6;
      float val = fb[o] + FC[nloc * 6 + o] + FC[(256 + nloc) * 6 + o];
      int n = n0 + nloc;
      int t = n / 24, v = n % 24;
      outp[(((size_t)(b0 + bl) * gT + t) * gV + v) * 6 + o] = val;
    }
  } else {
    // LDS-transpose + 16B plane writes; NSEG row-segments x {hi,lo} passes (ST in Bt).
    constexpr int CPB = CIO / 2;       // co-pair dwords per n-row
    constexpr int ROWS_P = (CIO == 256) ? 64 : 128;
    constexpr int NSEG = N_BLK / ROWS_P;
    constexpr int PITCH = CPB + 1;
    uint* ST = (uint*)&Bt[0];          // ROWS_P*PITCH*4 <= 33KB <= 45KB
    uint* oH32 = (uint*)oH;
    uint* oL32 = (uint*)oL;
    constexpr int QITERS = ROWS_P * CPB / 4 / 512;

#pragma unroll
    for (int seg = 0; seg < NSEG; ++seg) {
#pragma unroll
      for (int pass = 0; pass < 2; ++pass) {
        __syncthreads();
        int cl = wm * MF * 32;
#pragma unroll
        for (int mf = 0; mf < MF; ++mf) {
#pragma unroll
          for (int nf = 0; nf < NF; ++nf) {
            int rbase = wn * (NF * 32) + nf * 32;
            if (rbase >= seg * ROWS_P && rbase < (seg + 1) * ROWS_P) {
              int nl = rbase + (lane & 31) - seg * ROWS_P;
#pragma unroll
              for (int r = 0; r < 16; r += 2) {
                float z0 = acc[mf][nf][r], z1 = acc[mf][nf][r + 1];
                _Float16 a0 = (_Float16)z0, a1 = (_Float16)z1;
                if (pass == 1) { a0 = (_Float16)(z0 - (float)a0); a1 = (_Float16)(z1 - (float)a1); }
                half2v p2; p2[0] = a0; p2[1] = a1;
                int col2 = (cl + mf * 32 + 4 * (lane >> 5) + (r & 3) + 8 * (r >> 2)) >> 1;
                ST[nl * PITCH + col2] = *(uint*)&p2;
              }
            }
          }
        }
        __syncthreads();
        uint* dst = (pass == 0) ? oH32 : oL32;
#pragma unroll
        for (int i = 0; i < QITERS; ++i) {
          int idx = i * 512 + tid;                    // quad id
          int row = idx / (CPB / 4), c4 = (idx % (CPB / 4)) * 4;
          uint4 v;
          v.x = ST[row * PITCH + c4 + 0];
          v.y = ST[row * PITCH + c4 + 1];
          v.z = ST[row * PITCH + c4 + 2];
          v.w = ST[row * PITCH + c4 + 3];
          *(uint4*)(dst + ((size_t)blgN + n0 + seg * ROWS_P + row) * (CIO / 2) + c4) = v;
        }
      }
    }
  }
}

// ============================= host =============================
extern "C" void kernel_launch(void* const* d_in, const int* in_sizes, int n_in,
                              void* d_out, int out_size, void* d_ws, size_t ws_size,
                              hipStream_t stream) {
  const float* x    = (const float*)d_in[0];
  const float* A    = (const float*)d_in[1];
  const float* dbg  = (const float*)d_in[2];
  const float* dbb  = (const float*)d_in[3];
  const float* ei0  = (const float*)d_in[4];
  const float* ei1  = (const float*)d_in[5];
  const float* ei2  = (const float*)d_in[6];
  const float* w0g  = (const float*)d_in[7];
  const float* gb0  = (const float*)d_in[8];
  const float* g10  = (const float*)d_in[9];
  const float* b10  = (const float*)d_in[10];
  const float* tw0  = (const float*)d_in[11];
  const float* tb0  = (const float*)d_in[12];
  const float* g20  = (const float*)d_in[13];
  const float* b20  = (const float*)d_in[14];
  const float* w1g  = (const float*)d_in[15];
  const float* gb1  = (const float*)d_in[16];
  const float* g11  = (const float*)d_in[17];
  const float* b11  = (const float*)d_in[18];
  const float* tw1  = (const float*)d_in[19];
  const float* tb1  = (const float*)d_in[20];
  const float* g21  = (const float*)d_in[21];
  const float* b21  = (const float*)d_in[22];
  const float* rw1  = (const float*)d_in[23];
  const float* rb1  = (const float*)d_in[24];
  const float* rg1  = (const float*)d_in[25];
  const float* rbb1 = (const float*)d_in[26];
  const float* w2g  = (const float*)d_in[27];
  const float* gb2  = (const float*)d_in[28];
  const float* g12  = (const float*)d_in[29];
  const float* b12  = (const float*)d_in[30];
  const float* tw2  = (const float*)d_in[31];
  const float* tb2  = (const float*)d_in[32];
  const float* g22  = (const float*)d_in[33];
  const float* b22  = (const float*)d_in[34];
  const float* rw2  = (const float*)d_in[35];
  const float* rb2  = (const float*)d_in[36];
  const float* rg2  = (const float*)d_in[37];
  const float* rbb2 = (const float*)d_in[38];
  const float* fw   = (const float*)d_in[39];
  const float* fb   = (const float*)d_in[40];
  float* outp = (float*)d_out;
  float* ws = (float*)d_ws;

  // ws layout (floats)
  size_t off = 0;
  auto alloc = [&](size_t n) { size_t o = off; off += n; return o; };
  size_t oAE  = alloc(3 * 1728);
  size_t oCS  = alloc(3 * 72);
  size_t oA0  = alloc((size_t)1280 * 512 / 2);  // tcn0 frags
  size_t oA1  = alloc((size_t)320 * 512 / 2);
  size_t oA2  = alloc((size_t)80 * 512 / 2);
  size_t oWz1 = alloc((size_t)512 * 512 / 2);   // 512 frags * 512 halves
  size_t oWz2 = alloc((size_t)128 * 512 / 2);
  off = (off + 3) & ~(size_t)3;

  // per batch (floats/n): planes buf1 256 + planes buf2 256 + res rows 128 = 640
  const size_t perBatchBytes = (size_t)gN * 640 * 4;   // 15.73 MB
  int Bc = 32;
  while (Bc > 1 && off * 4 + (size_t)Bc * perBatchBytes > ws_size) Bc >>= 1;
  int NBc = Bc * gN;

  float* B1 = ws + off;
  float* B2 = B1 + (size_t)NBc * 256;
  float* Rb = B2 + (size_t)NBc * 256;          // res rows [<=128][NBc]
  _Float16* b1h = (_Float16*)B1;
  _Float16* b2h = (_Float16*)B2;
  _Float16* A0 = (_Float16*)(ws + oA0);
  _Float16* A1 = (_Float16*)(ws + oA1);
  _Float16* A2 = (_Float16*)(ws + oA2);
  _Float16* Wz1 = (_Float16*)(ws + oWz1);
  _Float16* Wz2 = (_Float16*)(ws + oWz2);

  // ---- prep ----
  k_prep_aeff<<<21, 256, 0, stream>>>(A, ei0, ei1, ei2, ws + oAE, ws + oCS);
  k_prep_twf<<<320, 256, 0, stream>>>(tw0, A0, 256, 8);
  k_prep_twf<<<80, 256, 0, stream>>>(tw1, A1, 128, 4);
  k_prep_twf<<<20, 256, 0, stream>>>(tw2, A2, 64, 2);
  k_pack_wz<<<128, 256, 0, stream>>>(w1g, rw1, Wz1, 256, 8, 384);  // M=512,K=256
  k_pack_wz<<<32, 256, 0, stream>>>(w2g, rw2, Wz2, 128, 4, 192);   // M=256,K=128

  for (int b0 = 0; b0 < 32; b0 += Bc) {
    // layer 0: gcn0 -> P1(256); tcn0 -> P2(256)
    k_gcn0<<<dim3(gT / 4, Bc), 256, 0, stream>>>(x, ws + oAE, ws + oCS, dbg, dbb,
                                                 w0g, gb0, g10, b10,
                                                 b1h, b1h + (size_t)NBc * 256, b0);
    k_tcn_mfma<256, 2, false><<<dim3(24, 1, Bc), 512, 0, stream>>>(
        b1h, b1h + (size_t)NBc * 256, A0, tb0, g20, b20,
        nullptr, nullptr, nullptr, nullptr,
        b2h, b2h + (size_t)NBc * 256, nullptr, nullptr, nullptr, 0, NBc);
    // layer 1: fused gcn (P2 -> P1 planes + res rows); tcn1(P1 + res) -> P2
    k_gcnfuse<256, 128><<<dim3(NBc / 96), 512, 0, stream>>>(
        b2h, b2h + (size_t)NBc * 256, Wz1,
        ws + oAE + 1728, ws + oCS + 72, gb1, g11, b11,
        b1h, b1h + (size_t)NBc * 128, Rb, NBc);
    k_tcn_mfma<128, 2, false><<<dim3(24, 1, Bc), 512, 0, stream>>>(
        b1h, b1h + (size_t)NBc * 128, A1, tb1, g21, b21,
        Rb, rb1, rg1, rbb1,
        b2h, b2h + (size_t)NBc * 128, nullptr, nullptr, nullptr, 0, NBc);
    // layer 2
    k_gcnfuse<128, 64><<<dim3(NBc / 96), 512, 0, stream>>>(
        b2h, b2h + (size_t)NBc * 128, Wz2,
        ws + oAE + 2 * 1728, ws + oCS + 144, gb2, g12, b12,
        b1h, b1h + (size_t)NBc * 64, Rb, NBc);
    // tcn2 + fused fc -> d_out directly
    k_tcn_mfma<64, 1, true><<<dim3(24, 1, Bc), 512, 0, stream>>>(
        b1h, b1h + (size_t)NBc * 64, A2, tb2, g22, b22,
        Rb, rb2, rg2, rbb2,
        nullptr, nullptr, fw, fb, outp, b0, NBc);
  }
  (void)in_sizes; (void)n_in; (void)out_size;
}

// Round 20
// 1321.070 us; speedup vs baseline: 1.2452x; 1.2452x over previous
//
#include <hip/hip_runtime.h>

typedef _Float16 half8 __attribute__((ext_vector_type(8)));
typedef _Float16 half2v __attribute__((ext_vector_type(2)));
typedef float floatx16 __attribute__((ext_vector_type(16)));

static constexpr int gT = 256;      // time steps
static constexpr int gV = 24;       // graph nodes
static constexpr int gN = gT * gV;  // 6144 columns per batch
static constexpr float BN_INV = 0.99999500003749969f; // 1/sqrt(1+1e-5)

#define GLOAD_LDS16(g, l)                                            \
  __builtin_amdgcn_global_load_lds(                                  \
      (const __attribute__((address_space(1))) unsigned int*)(g),    \
      (__attribute__((address_space(3))) unsigned int*)(l), 16, 0, 0)

// ============================= prep kernels =============================
__global__ __launch_bounds__(256) void k_prep_aeff(
    const float* __restrict__ A, const float* __restrict__ e0,
    const float* __restrict__ e1, const float* __restrict__ e2,
    float* __restrict__ aeff, float* __restrict__ csum)
{
  int tid = blockIdx.x * 256 + threadIdx.x;
  if (tid < 3 * 1728) {
    int l = tid / 1728, r = tid % 1728;
    const float* e = (l == 0) ? e0 : ((l == 1) ? e1 : e2);
    aeff[tid] = A[r] * e[r];
  }
  if (tid < 3 * 72) {
    int l = tid / 72, r = tid % 72;
    int k = r / 24, w = r % 24;
    const float* e = (l == 0) ? e0 : ((l == 1) ? e1 : e2);
    float s = 0.f;
    for (int v = 0; v < 24; ++v) { int idx = (k * 24 + v) * 24 + w; s += A[idx] * e[idx]; }
    csum[tid] = s;
  }
}

// Pack tcn weights into MFMA A-fragment order, f16 hi/lo split.
__global__ __launch_bounds__(256) void k_prep_twf(
    const float* __restrict__ tw, _Float16* __restrict__ out, int CI, int KT)
{
  int g = blockIdx.x * 256 + threadIdx.x;
  int fid = g >> 6, lane = g & 63;
  int pl = fid & 1;
  int f2 = fid >> 1;
  int dt = f2 % 5;
  int f3 = f2 / 5;
  int ks = f3 & 1;
  int f4 = f3 >> 1;
  int kt = f4 % KT;
  int mt = f4 / KT;
  int m = mt * 32 + (lane & 31);
  int kb = kt * 32 + ks * 16 + ((lane >> 5) << 3);
  half8 o;
#pragma unroll
  for (int e = 0; e < 8; ++e) {
    float v = tw[((size_t)m * CI + (kb + e)) * 5 + dt];
    _Float16 h = (_Float16)v;
    o[e] = pl ? (_Float16)(v - (float)h) : h;
  }
  *(half8*)(out + ((size_t)fid * 64 + lane) * 8) = o;
}

// Pack gcn W_big = [Wg(3*COUT rows); Wr(COUT rows)] into fuse A-fragments.
__global__ __launch_bounds__(256) void k_pack_wz(
    const float* __restrict__ Wg, const float* __restrict__ Wr,
    _Float16* __restrict__ out, int CIN, int KT, int M3)
{
  int g = blockIdx.x * 256 + threadIdx.x;
  int fid = g >> 6, lane = g & 63;
  int pl = fid & 1;
  int ks = (fid >> 1) & 1;
  int rest = fid >> 2;
  int kt = rest % KT;
  int mt = rest / KT;
  int m = mt * 32 + (lane & 31);
  int kb = kt * 32 + ks * 16 + ((lane >> 5) << 3);
  const float* row = (m < M3) ? (Wg + (size_t)m * CIN) : (Wr + (size_t)(m - M3) * CIN);
  half8 o;
#pragma unroll
  for (int e = 0; e < 8; ++e) {
    float v = row[kb + e];
    _Float16 h = (_Float16)v;
    o[e] = pl ? (_Float16)(v - (float)h) : h;
  }
  *(half8*)(out + ((size_t)fid * 64 + lane) * 8) = o;
}

// ============================= layer 0 GCN (4 t per block) =============================
__global__ __launch_bounds__(256) void k_gcn0(
    const float* __restrict__ x,      // [B][T][24][3]
    const float* __restrict__ aeff,   // [3][24][24]
    const float* __restrict__ csum,   // [3][24]
    const float* __restrict__ dbg, const float* __restrict__ dbb,  // [72]
    const float* __restrict__ W0,     // [768][3]
    const float* __restrict__ gb0,    // [768]
    const float* __restrict__ g1, const float* __restrict__ b1,    // [256]
    _Float16* __restrict__ yh, _Float16* __restrict__ yl,          // [NBc][256]
    int b0)
{
  __shared__ float xbn[72];      // [cin][v]
  __shared__ float XA[216];      // [(k*3+ci)][w]
  __shared__ float WL[2304];
  __shared__ float tile[256 * 25];
  int t0 = blockIdx.x * 4, bl = blockIdx.y, tid = threadIdx.x;
  int b = b0 + bl;
  int c = tid;

  for (int i = tid; i < 2304; i += 256) WL[i] = W0[i];

  for (int tr = 0; tr < 4; ++tr) {
    int t = t0 + tr;
    __syncthreads();                 // WL ready (tr=0); xbn/tile free (tr>0)
    if (tid < 72) {
      int v = tid / 3, cin = tid % 3;
      float xv = x[(((size_t)b * gT + t) * gV + v) * 3 + cin];
      xbn[cin * 24 + v] = xv * (BN_INV * dbg[tid]) + dbb[tid];
    }
    __syncthreads();
    if (tid < 216) {
      int k = tid / 72, r = tid % 72, ci = r / 24, w = r % 24;
      const float* Ak = aeff + k * 576;
      float s = 0.f;
#pragma unroll
      for (int v = 0; v < 24; ++v) s += xbn[ci * 24 + v] * Ak[v * 24 + w];
      XA[tid] = s;
    }
    __syncthreads();

    float acc[24];
#pragma unroll
    for (int w = 0; w < 24; ++w) acc[w] = 0.f;
#pragma unroll
    for (int k = 0; k < 3; ++k) {
#pragma unroll
      for (int ci = 0; ci < 3; ++ci) {
        float wv = WL[(k * 256 + c) * 3 + ci];
#pragma unroll
        for (int w = 0; w < 24; ++w) acc[w] += wv * XA[(k * 3 + ci) * 24 + w];
      }
      float gv = gb0[k * 256 + c];
#pragma unroll
      for (int w = 0; w < 24; ++w) acc[w] += gv * csum[k * 24 + w];
    }
    float s1 = BN_INV * g1[c], o1 = b1[c];
#pragma unroll
    for (int w = 0; w < 24; ++w) tile[c * 25 + w] = fmaxf(acc[w] * s1 + o1, 0.f);
    __syncthreads();

    // vectorized plane writes: 8 c per thread, half8 (16B) stores; slab contiguous.
    size_t nb = ((size_t)bl * gN + (size_t)t * 24);
    _Float16* dhB = yh + nb * 256;
    _Float16* dlB = yl + nb * 256;
#pragma unroll
    for (int it = 0; it < 3; ++it) {
      int idx = it * 256 + tid;          // < 768 = 24 w * 32 c-octets
      int w = idx >> 5;
      int c0 = (idx & 31) * 8;
      half8 vh, vl;
#pragma unroll
      for (int q = 0; q < 8; ++q) {
        float v = tile[(c0 + q) * 25 + w];
        _Float16 hh = (_Float16)v;
        vh[q] = hh;
        vl[q] = (_Float16)(v - (float)hh);
      }
      *(half8*)(dhB + (size_t)w * 256 + c0) = vh;
      *(half8*)(dlB + (size_t)w * 256 + c0) = vl;
    }
  }
}

// ============================= fused gcn: Z-GEMM + A-contraction =============================
template <int CIN, int COUT>
__global__ __launch_bounds__(512) void k_gcnfuse(
    const _Float16* __restrict__ pH, const _Float16* __restrict__ pL, // [NBc][CIN]
    const _Float16* __restrict__ Wf,
    const float* __restrict__ aeffL, const float* __restrict__ csumL,
    const float* __restrict__ gb, const float* __restrict__ g1, const float* __restrict__ b1,
    _Float16* __restrict__ oH, _Float16* __restrict__ oL,  // [NBc][COUT]
    float* __restrict__ res_out,                           // [COUT][NBc] raw Z res rows
    int NBc)
{
  constexpr int KT = CIN / 32;
  constexpr int M = 4 * COUT;
  constexpr int M3 = 3 * COUT;
  constexpr int MT = M / 256;           // mt-tiles per wave (8 waves): L1: 2, L2: 1
  constexpr int BSTG_FL = 2 * 2 * 96 * 40 / 2;  // dbuf B staging, in floats (7680)
  constexpr int ZLW = M * 25;                   // ZL floats (L1: 12800, L2: 6400)
  constexpr int UNIW = (ZLW > BSTG_FL) ? ZLW : BSTG_FL;
  __shared__ float UNI[UNIW];
  __shared__ float AL[1728];
  __shared__ float csL[72];
  __shared__ __align__(16) _Float16 YST[24 * COUT * 2];  // staged y slab: hi | lo planes
  _Float16* Bb = (_Float16*)UNI;
  float* ZL = UNI;

  int tid = threadIdx.x, w = tid >> 6, lane = tid & 63;
  int n0 = blockIdx.x * 96;

  for (int i = tid; i < 1728; i += 512) AL[i] = aeffL[i];
  if (tid < 72) csL[tid] = csumL[tid];

  floatx16 acc[MT][3] = {};

  uint4 pf[2];
  auto PREF = [&](int kt) {
#pragma unroll
    for (int it = 0; it < 2; ++it) {
      int task = it * 512 + tid;       // 768 = 96 rows * 2 planes * 4 segs
      if (task < 768) {
        int row = task >> 3, pl = (task >> 2) & 1, seg = task & 3;
        pf[it] = *(const uint4*)((pl ? pL : pH) + (size_t)(n0 + row) * CIN + kt * 32 + seg * 8);
      }
    }
  };
  auto WRITE = [&](int buf) {
#pragma unroll
    for (int it = 0; it < 2; ++it) {
      int task = it * 512 + tid;
      if (task < 768) {
        int row = task >> 3, pl = (task >> 2) & 1, seg = task & 3;
        *(uint4*)(Bb + (((size_t)buf * 2 + pl) * 96 + row) * 40 + seg * 8) = pf[it];
      }
    }
  };

  PREF(0); WRITE(0); __syncthreads();
  int cur = 0;
  for (int kt = 0; kt < KT; ++kt) {
    if (kt + 1 < KT) PREF(kt + 1);     // loads fly during MFMA below
    const _Float16* BH = Bb + (size_t)(cur * 2 + 0) * 96 * 40;
    const _Float16* BL2 = Bb + (size_t)(cur * 2 + 1) * 96 * 40;
    __builtin_amdgcn_s_setprio(1);
#pragma unroll
    for (int ks = 0; ks < 2; ++ks) {
      int koff = ks * 16 + ((lane >> 5) << 3);
      int rowb = lane & 31;
      half8 bh[3], bl[3];
#pragma unroll
      for (int nf = 0; nf < 3; ++nf) {
        bh[nf] = *(const half8*)(BH + (rowb + nf * 32) * 40 + koff);
        bl[nf] = *(const half8*)(BL2 + (rowb + nf * 32) * 40 + koff);
      }
#pragma unroll
      for (int mti = 0; mti < MT; ++mti) {
        int mt = w * MT + mti;
        int fid = ((mt * KT + kt) * 2 + ks) * 2;
        half8 ah = *(const half8*)(Wf + ((size_t)fid * 64 + lane) * 8);
        half8 al = *(const half8*)(Wf + ((size_t)(fid + 1) * 64 + lane) * 8);
#pragma unroll
        for (int nf = 0; nf < 3; ++nf) {
          acc[mti][nf] = __builtin_amdgcn_mfma_f32_32x32x16_f16(ah, bh[nf], acc[mti][nf], 0, 0, 0);
          acc[mti][nf] = __builtin_amdgcn_mfma_f32_32x32x16_f16(ah, bl[nf], acc[mti][nf], 0, 0, 0);
          acc[mti][nf] = __builtin_amdgcn_mfma_f32_32x32x16_f16(al, bh[nf], acc[mti][nf], 0, 0, 0);
        }
      }
    }
    __builtin_amdgcn_s_setprio(0);
    if (kt + 1 < KT) WRITE(cur ^ 1);   // vmcnt wait lands here, after MFMA
    __syncthreads();
    cur ^= 1;
  }

  constexpr int SUBS = 512 / COUT;     // L1: 4, L2: 8
  constexpr int WR = 24 / SUBS;        // L1: 6, L2: 3
  int c = tid & (COUT - 1);
  int w0 = (tid / COUT) * WR;
  float s1 = BN_INV * g1[c], o1 = b1[c];
  float gv0 = gb[c], gv1 = gb[COUT + c], gv2 = gb[2 * COUT + c];

  for (int tr = 0; tr < 4; ++tr) {
    __syncthreads();
#pragma unroll
    for (int mti = 0; mti < MT; ++mti) {
#pragma unroll
      for (int nf = 0; nf < 3; ++nf) {
        int nloc = nf * 32 + (lane & 31) - tr * 24;
        if (nloc >= 0 && nloc < 24) {
          int mb_ = (w * MT + mti) * 32 + 4 * (lane >> 5);
#pragma unroll
          for (int r = 0; r < 16; ++r)
            ZL[(mb_ + (r & 3) + 8 * (r >> 2)) * 25 + nloc] = acc[mti][nf][r];
        }
      }
    }
    __syncthreads();
    float y[WR];
#pragma unroll
    for (int j = 0; j < WR; ++j) y[j] = 0.f;
#pragma unroll
    for (int k = 0; k < 3; ++k) {
#pragma unroll
      for (int v = 0; v < 24; ++v) {
        float zr = ZL[(k * COUT + c) * 25 + v];
        const float* ap = &AL[k * 576 + v * 24 + w0];
#pragma unroll
        for (int j = 0; j < WR; ++j) y[j] += zr * ap[j];
      }
    }
#pragma unroll
    for (int j = 0; j < WR; ++j) {
      int ww = w0 + j;
      float bias = gv0 * csL[ww] + gv1 * csL[24 + ww] + gv2 * csL[48 + ww];
      float yv = fmaxf((y[j] + bias) * s1 + o1, 0.f);
      _Float16 h = (_Float16)yv;
      YST[ww * COUT + c] = h;
      YST[24 * COUT + ww * COUT + c] = (_Float16)(yv - (float)h);
    }
    __syncthreads();
    // bulk 16B plane writes (slab contiguous in global) + float4 res writes
    constexpr int QT = 24 * COUT / 8;        // half8 per plane
    size_t nbase = (size_t)n0 + tr * 24;
    for (int idx = tid; idx < 2 * QT; idx += 512) {
      int plane = idx / QT, q = idx - plane * QT;
      _Float16* dst = (plane ? oL : oH) + nbase * COUT + q * 8;
      *(half8*)dst = *(half8*)(YST + plane * 24 * COUT + q * 8);
    }
    for (int idx = tid; idx < COUT * 6; idx += 512) {
      int cc = idx / 6, q = idx - cc * 6;
      float4 v4;
      v4.x = ZL[(M3 + cc) * 25 + 4 * q + 0];
      v4.y = ZL[(M3 + cc) * 25 + 4 * q + 1];
      v4.z = ZL[(M3 + cc) * 25 + 4 * q + 2];
      v4.w = ZL[(M3 + cc) * 25 + 4 * q + 3];
      *(float4*)(res_out + (size_t)cc * NBc + nbase + 4 * q) = v4;
    }
  }
}

// ============================= temporal conv (MFMA, 512 threads / 8 waves) =============================
// Block covers full M=CIO; waves tile (wm,wn) over M x 128-col N. Counted-vmcnt dbuf.
// FUSE_FC: apply fc to post-relu h in-register, reduce, write d_out directly.
template <int CIO, int MF, bool FUSE_FC>
__global__ __launch_bounds__(512) void k_tcn_mfma(
    const _Float16* __restrict__ yH, const _Float16* __restrict__ yL, // [NBc][CIO]
    const _Float16* __restrict__ Apack,
    const float* __restrict__ tb, const float* __restrict__ g2, const float* __restrict__ b2,
    const float* __restrict__ Zres,   // res rows [CIO][NBc] raw, or nullptr
    const float* __restrict__ rb, const float* __restrict__ rg, const float* __restrict__ rbb,
    _Float16* __restrict__ oH, _Float16* __restrict__ oL,  // [NBc][CIO] (unused if FUSE_FC)
    const float* __restrict__ fw, const float* __restrict__ fb,  // fc params (FUSE_FC)
    float* __restrict__ outp, int b0,
    int NBc)
{
  constexpr int KT = CIO / 32;
  constexpr int M = CIO;
  constexpr int NWAVE_M = M / (MF * 32);      // 256:4  128:2  64:2
  constexpr int NWAVE_N = 8 / NWAVE_M;        // 256:2  128:4  64:4
  constexpr int NF = 128 / (32 * NWAVE_N);    // 256:2  128:1  64:1
  constexpr int NROW = 224;                   // 128 cols + 96 halo rows
  __shared__ _Float16 Bt[2][NROW * 64];       // 2 x 28672 B
  __shared__ float scL[CIO], ofL[CIO], tbL[CIO], rscL[CIO], rofL[CIO], rbvL[CIO];
  __shared__ float fwL[FUSE_FC ? 384 : 4];
  int bx = blockIdx.x, bl = blockIdx.z;
  int tid = threadIdx.x, w = tid >> 6, lane = tid & 63;
  int wn = w % NWAVE_N, wm = w / NWAVE_N;
  int n0 = bx * 128;
  bool interior = (bx > 0) && (bx < 47);

  for (int i = tid; i < CIO; i += 512) {
    scL[i] = BN_INV * g2[i]; ofL[i] = b2[i]; tbL[i] = tb[i];
    if (Zres) { rscL[i] = BN_INV * rg[i]; rofL[i] = rbb[i]; rbvL[i] = rb[i]; }
  }
  if (FUSE_FC) { for (int i = tid; i < 384; i += 512) fwL[i] = fw[i]; }

  floatx16 acc[MF][NF] = {};
  const _Float16* ybH = yH + (size_t)bl * gN * CIO;
  const _Float16* ybL = yL + (size_t)bl * gN * CIO;
  int mt_base = wm * MF;

  auto ISSUE = [&](int kt, int buf) {   // async gload_lds; slots w*4+it, 28 used
#pragma unroll
    for (int it = 0; it < 4; ++it) {
      int slot = w * 4 + it;
      if (slot < 28) {
        int T = slot * 64 + lane;
        int r = T >> 3, s = T & 7;
        int sl = s ^ (r & 7);
        int pl = sl >> 2, seg = sl & 3;
        int n = n0 - 48 + r;
        const _Float16* src = (pl ? ybL : ybH) + (size_t)n * CIO + kt * 32 + seg * 8;
        GLOAD_LDS16(src, &Bt[buf][(size_t)slot * 512]);
      }
    }
  };
  auto ISSUE_EDGE = [&](int kt, int buf) {  // reg-staged, zero-filled halo
#pragma unroll
    for (int it = 0; it < 4; ++it) {
      int slot = w * 4 + it;
      if (slot < 28) {
        int T = slot * 64 + lane;
        int r = T >> 3, s = T & 7;
        int sl = s ^ (r & 7);
        int pl = sl >> 2, seg = sl & 3;
        int n = n0 - 48 + r;
        uint4 vv = make_uint4(0u, 0u, 0u, 0u);
        if (n >= 0 && n < gN)
          vv = *(const uint4*)((pl ? ybL : ybH) + (size_t)n * CIO + kt * 32 + seg * 8);
        *(uint4*)(&Bt[buf][(size_t)T * 8]) = vv;
      }
    }
  };
  auto COMPUTE = [&](int kt, int buf) {
    const _Float16* B = &Bt[buf][0];
    __builtin_amdgcn_s_setprio(1);
#pragma unroll
    for (int dt = 0; dt < 5; ++dt) {
#pragma unroll
      for (int ks = 0; ks < 2; ++ks) {
        int seg = ks * 2 + (lane >> 5);
        half8 bh[NF], blv[NF];
#pragma unroll
        for (int nf = 0; nf < NF; ++nf) {
          int rr = wn * (NF * 32) + nf * 32 + dt * 24 + (lane & 31);
          bh[nf]  = *(const half8*)(B + rr * 64 + (((0 + seg) ^ (rr & 7)) * 8));
          blv[nf] = *(const half8*)(B + rr * 64 + (((4 + seg) ^ (rr & 7)) * 8));
        }
#pragma unroll
        for (int mf = 0; mf < MF; ++mf) {
          int fid = ((((mt_base + mf) * KT + kt) * 2 + ks) * 5 + dt) * 2;
          half8 ah = *(const half8*)(Apack + ((size_t)fid * 64 + lane) * 8);
          half8 al = *(const half8*)(Apack + ((size_t)(fid + 1) * 64 + lane) * 8);
#pragma unroll
          for (int nf = 0; nf < NF; ++nf) {
            acc[mf][nf] = __builtin_amdgcn_mfma_f32_32x32x16_f16(ah, bh[nf], acc[mf][nf], 0, 0, 0);
            acc[mf][nf] = __builtin_amdgcn_mfma_f32_32x32x16_f16(ah, blv[nf], acc[mf][nf], 0, 0, 0);
            acc[mf][nf] = __builtin_amdgcn_mfma_f32_32x32x16_f16(al, bh[nf], acc[mf][nf], 0, 0, 0);
          }
        }
      }
    }
    __builtin_amdgcn_s_setprio(0);
  };

  if (interior) {
    ISSUE(0, 0);
    int cur = 0;
    for (int kt = 0; kt < KT; ++kt) {
      __builtin_amdgcn_sched_barrier(0);
      if (kt + 1 < KT) ISSUE(kt + 1, cur ^ 1);
      __builtin_amdgcn_sched_barrier(0);
      if (kt + 1 < KT) asm volatile("s_waitcnt vmcnt(4)" ::: "memory");
      else             asm volatile("s_waitcnt vmcnt(0)" ::: "memory");
      __builtin_amdgcn_sched_barrier(0);
      __builtin_amdgcn_s_barrier();
      __builtin_amdgcn_sched_barrier(0);
      COMPUTE(kt, cur);
      asm volatile("s_waitcnt lgkmcnt(0)" ::: "memory");
      __builtin_amdgcn_sched_barrier(0);
      __builtin_amdgcn_s_barrier();
      cur ^= 1;
    }
  } else {
    for (int kt = 0; kt < KT; ++kt) {
      __syncthreads();
      ISSUE_EDGE(kt, 0);
      __syncthreads();
      COMPUTE(kt, 0);
    }
  }

  // epilogue: acc -> z (bias + bn2 + res + relu), in place
  int blgN = bl * gN;
#pragma unroll
  for (int mf = 0; mf < MF; ++mf) {
    int m32 = wm * MF * 32 + mf * 32 + 4 * (lane >> 5);
#pragma unroll
    for (int nf = 0; nf < NF; ++nf) {
      int n = n0 + wn * (NF * 32) + nf * 32 + (lane & 31);
      size_t nflat = (size_t)blgN + n;
#pragma unroll
      for (int r = 0; r < 16; ++r) {
        int co = m32 + (r & 3) + 8 * (r >> 2);
        float z = (acc[mf][nf][r] + tbL[co]) * scL[co] + ofL[co];
        if (Zres) z += (Zres[(size_t)co * NBc + nflat] + rbvL[co]) * rscL[co] + rofL[co];
        acc[mf][nf][r] = fmaxf(z, 0.f);
      }
    }
  }

  if constexpr (FUSE_FC) {
    // MF=1, NF=1, NWAVE_M=2 (wm 0..1), NWAVE_N=4 (wn 0..3).
    __syncthreads();                   // Bt free
    float* FC = (float*)&Bt[0][0];     // [2 wm][128 n][6]
    float p[6];
#pragma unroll
    for (int o = 0; o < 6; ++o) p[o] = 0.f;
    int m32 = wm * 32 + 4 * (lane >> 5);
#pragma unroll
    for (int r = 0; r < 16; ++r) {
      int co = m32 + (r & 3) + 8 * (r >> 2);
      float z = acc[0][0][r];
#pragma unroll
      for (int o = 0; o < 6; ++o) p[o] += fwL[o * 64 + co] * z;
    }
#pragma unroll
    for (int o = 0; o < 6; ++o) p[o] += __shfl_xor(p[o], 32);
    if (lane < 32) {
      int nloc = wn * 32 + lane;
#pragma unroll
      for (int o = 0; o < 6; ++o)
        FC[(wm * 128 + nloc) * 6 + o] = p[o];
    }
    __syncthreads();
    for (int idx = tid; idx < 768; idx += 512) {
      int nloc = idx / 6, o = idx % 6;
      float val = fb[o] + FC[nloc * 6 + o] + FC[(128 + nloc) * 6 + o];
      int n = n0 + nloc;
      int t = n / 24, v = n % 24;
      outp[(((size_t)(b0 + bl) * gT + t) * gV + v) * 6 + o] = val;
    }
  } else {
    // LDS-transpose + 16B plane writes.  ST rows per pass chosen to fit Bt.
    constexpr int CPB = CIO / 2;       // co-pair dwords per n-row
    constexpr int NHALF = (128 * (CPB + 1) * 4 > 2 * NROW * 64 * 2) ? 2 : 1;
    constexpr int ROWS_P = 128 / NHALF;
    constexpr int PITCH = CPB + 1;
    uint* ST = (uint*)&Bt[0][0];
    uint* oH32 = (uint*)oH;
    uint* oL32 = (uint*)oL;
    constexpr int QITERS = ROWS_P * CPB / 4 / 512;

#pragma unroll
    for (int half = 0; half < NHALF; ++half) {
#pragma unroll
      for (int pass = 0; pass < 2; ++pass) {
        __syncthreads();
        if (NHALF == 1 || wn == half) {
          int cl = wm * MF * 32;
#pragma unroll
          for (int mf = 0; mf < MF; ++mf) {
#pragma unroll
            for (int nf = 0; nf < NF; ++nf) {
              int nl = wn * (NF * 32) + nf * 32 + (lane & 31) - half * ROWS_P;
#pragma unroll
              for (int r = 0; r < 16; r += 2) {
                float z0 = acc[mf][nf][r], z1 = acc[mf][nf][r + 1];
                _Float16 a0 = (_Float16)z0, a1 = (_Float16)z1;
                if (pass == 1) { a0 = (_Float16)(z0 - (float)a0); a1 = (_Float16)(z1 - (float)a1); }
                half2v p2; p2[0] = a0; p2[1] = a1;
                int col2 = (cl + mf * 32 + 4 * (lane >> 5) + (r & 3) + 8 * (r >> 2)) >> 1;
                ST[nl * PITCH + col2] = *(uint*)&p2;
              }
            }
          }
        }
        __syncthreads();
        uint* dst = (pass == 0) ? oH32 : oL32;
#pragma unroll
        for (int i = 0; i < QITERS; ++i) {
          int idx = i * 512 + tid;                    // quad id
          int row = idx / (CPB / 4), c4 = (idx % (CPB / 4)) * 4;
          uint4 v;
          v.x = ST[row * PITCH + c4 + 0];
          v.y = ST[row * PITCH + c4 + 1];
          v.z = ST[row * PITCH + c4 + 2];
          v.w = ST[row * PITCH + c4 + 3];
          *(uint4*)(dst + ((size_t)blgN + n0 + half * ROWS_P + row) * (CIO / 2) + c4) = v;
        }
      }
    }
  }
}

// ============================= host =============================
extern "C" void kernel_launch(void* const* d_in, const int* in_sizes, int n_in,
                              void* d_out, int out_size, void* d_ws, size_t ws_size,
                              hipStream_t stream) {
  const float* x    = (const float*)d_in[0];
  const float* A    = (const float*)d_in[1];
  const float* dbg  = (const float*)d_in[2];
  const float* dbb  = (const float*)d_in[3];
  const float* ei0  = (const float*)d_in[4];
  const float* ei1  = (const float*)d_in[5];
  const float* ei2  = (const float*)d_in[6];
  const float* w0g  = (const float*)d_in[7];
  const float* gb0  = (const float*)d_in[8];
  const float* g10  = (const float*)d_in[9];
  const float* b10  = (const float*)d_in[10];
  const float* tw0  = (const float*)d_in[11];
  const float* tb0  = (const float*)d_in[12];
  const float* g20  = (const float*)d_in[13];
  const float* b20  = (const float*)d_in[14];
  const float* w1g  = (const float*)d_in[15];
  const float* gb1  = (const float*)d_in[16];
  const float* g11  = (const float*)d_in[17];
  const float* b11  = (const float*)d_in[18];
  const float* tw1  = (const float*)d_in[19];
  const float* tb1  = (const float*)d_in[20];
  const float* g21  = (const float*)d_in[21];
  const float* b21  = (const float*)d_in[22];
  const float* rw1  = (const float*)d_in[23];
  const float* rb1  = (const float*)d_in[24];
  const float* rg1  = (const float*)d_in[25];
  const float* rbb1 = (const float*)d_in[26];
  const float* w2g  = (const float*)d_in[27];
  const float* gb2  = (const float*)d_in[28];
  const float* g12  = (const float*)d_in[29];
  const float* b12  = (const float*)d_in[30];
  const float* tw2  = (const float*)d_in[31];
  const float* tb2  = (const float*)d_in[32];
  const float* g22  = (const float*)d_in[33];
  const float* b22  = (const float*)d_in[34];
  const float* rw2  = (const float*)d_in[35];
  const float* rb2  = (const float*)d_in[36];
  const float* rg2  = (const float*)d_in[37];
  const float* rbb2 = (const float*)d_in[38];
  const float* fw   = (const float*)d_in[39];
  const float* fb   = (const float*)d_in[40];
  float* outp = (float*)d_out;
  float* ws = (float*)d_ws;

  // ws layout (floats)
  size_t off = 0;
  auto alloc = [&](size_t n) { size_t o = off; off += n; return o; };
  size_t oAE  = alloc(3 * 1728);
  size_t oCS  = alloc(3 * 72);
  size_t oA0  = alloc((size_t)1280 * 512 / 2);  // tcn0 frags
  size_t oA1  = alloc((size_t)320 * 512 / 2);
  size_t oA2  = alloc((size_t)80 * 512 / 2);
  size_t oWz1 = alloc((size_t)512 * 512 / 2);   // 512 frags * 512 halves
  size_t oWz2 = alloc((size_t)128 * 512 / 2);
  off = (off + 3) & ~(size_t)3;

  // per batch (floats/n): planes buf1 256 + planes buf2 256 + res rows 128 = 640
  const size_t perBatchBytes = (size_t)gN * 640 * 4;   // 15.73 MB
  int Bc = 32;
  while (Bc > 1 && off * 4 + (size_t)Bc * perBatchBytes > ws_size) Bc >>= 1;
  int NBc = Bc * gN;

  float* B1 = ws + off;
  float* B2 = B1 + (size_t)NBc * 256;
  float* Rb = B2 + (size_t)NBc * 256;          // res rows [<=128][NBc]
  _Float16* b1h = (_Float16*)B1;
  _Float16* b2h = (_Float16*)B2;
  _Float16* A0 = (_Float16*)(ws + oA0);
  _Float16* A1 = (_Float16*)(ws + oA1);
  _Float16* A2 = (_Float16*)(ws + oA2);
  _Float16* Wz1 = (_Float16*)(ws + oWz1);
  _Float16* Wz2 = (_Float16*)(ws + oWz2);

  // ---- prep ----
  k_prep_aeff<<<21, 256, 0, stream>>>(A, ei0, ei1, ei2, ws + oAE, ws + oCS);
  k_prep_twf<<<320, 256, 0, stream>>>(tw0, A0, 256, 8);
  k_prep_twf<<<80, 256, 0, stream>>>(tw1, A1, 128, 4);
  k_prep_twf<<<20, 256, 0, stream>>>(tw2, A2, 64, 2);
  k_pack_wz<<<128, 256, 0, stream>>>(w1g, rw1, Wz1, 256, 8, 384);  // M=512,K=256
  k_pack_wz<<<32, 256, 0, stream>>>(w2g, rw2, Wz2, 128, 4, 192);   // M=256,K=128

  for (int b0 = 0; b0 < 32; b0 += Bc) {
    // layer 0: gcn0 -> P1(256); tcn0 -> P2(256)
    k_gcn0<<<dim3(gT / 4, Bc), 256, 0, stream>>>(x, ws + oAE, ws + oCS, dbg, dbb,
                                                 w0g, gb0, g10, b10,
                                                 b1h, b1h + (size_t)NBc * 256, b0);
    k_tcn_mfma<256, 2, false><<<dim3(48, 1, Bc), 512, 0, stream>>>(
        b1h, b1h + (size_t)NBc * 256, A0, tb0, g20, b20,
        nullptr, nullptr, nullptr, nullptr,
        b2h, b2h + (size_t)NBc * 256, nullptr, nullptr, nullptr, 0, NBc);
    // layer 1: fused gcn (P2 -> P1 planes + res rows); tcn1(P1 + res) -> P2
    k_gcnfuse<256, 128><<<dim3(NBc / 96), 512, 0, stream>>>(
        b2h, b2h + (size_t)NBc * 256, Wz1,
        ws + oAE + 1728, ws + oCS + 72, gb1, g11, b11,
        b1h, b1h + (size_t)NBc * 128, Rb, NBc);
    k_tcn_mfma<128, 2, false><<<dim3(48, 1, Bc), 512, 0, stream>>>(
        b1h, b1h + (size_t)NBc * 128, A1, tb1, g21, b21,
        Rb, rb1, rg1, rbb1,
        b2h, b2h + (size_t)NBc * 128, nullptr, nullptr, nullptr, 0, NBc);
    // layer 2
    k_gcnfuse<128, 64><<<dim3(NBc / 96), 512, 0, stream>>>(
        b2h, b2h + (size_t)NBc * 128, Wz2,
        ws + oAE + 2 * 1728, ws + oCS + 144, gb2, g12, b12,
        b1h, b1h + (size_t)NBc * 64, Rb, NBc);
    // tcn2 + fused fc -> d_out directly
    k_tcn_mfma<64, 1, true><<<dim3(48, 1, Bc), 512, 0, stream>>>(
        b1h, b1h + (size_t)NBc * 64, A2, tb2, g22, b22,
        Rb, rb2, rg2, rbb2,
        nullptr, nullptr, fw, fb, outp, b0, NBc);
  }
  (void)in_sizes; (void)n_in; (void)out_size;
}

// Round 21
// 1248.882 us; speedup vs baseline: 1.3171x; 1.0578x over previous
//
#include <hip/hip_runtime.h>

typedef _Float16 half8 __attribute__((ext_vector_type(8)));
typedef _Float16 half2v __attribute__((ext_vector_type(2)));
typedef float floatx16 __attribute__((ext_vector_type(16)));

static constexpr int gT = 256;      // time steps
static constexpr int gV = 24;       // graph nodes
static constexpr int gN = gT * gV;  // 6144 columns per batch
static constexpr float BN_INV = 0.99999500003749969f; // 1/sqrt(1+1e-5)

#define GLOAD_LDS16(g, l)                                            \
  __builtin_amdgcn_global_load_lds(                                  \
      (const __attribute__((address_space(1))) unsigned int*)(g),    \
      (__attribute__((address_space(3))) unsigned int*)(l), 16, 0, 0)

// ============================= prep kernels =============================
__global__ __launch_bounds__(256) void k_prep_aeff(
    const float* __restrict__ A, const float* __restrict__ e0,
    const float* __restrict__ e1, const float* __restrict__ e2,
    float* __restrict__ aeff, float* __restrict__ csum)
{
  int tid = blockIdx.x * 256 + threadIdx.x;
  if (tid < 3 * 1728) {
    int l = tid / 1728, r = tid % 1728;
    const float* e = (l == 0) ? e0 : ((l == 1) ? e1 : e2);
    aeff[tid] = A[r] * e[r];
  }
  if (tid < 3 * 72) {
    int l = tid / 72, r = tid % 72;
    int k = r / 24, w = r % 24;
    const float* e = (l == 0) ? e0 : ((l == 1) ? e1 : e2);
    float s = 0.f;
    for (int v = 0; v < 24; ++v) { int idx = (k * 24 + v) * 24 + w; s += A[idx] * e[idx]; }
    csum[tid] = s;
  }
}

// Pack tcn weights into MFMA A-fragment order, f16 hi/lo split.
__global__ __launch_bounds__(256) void k_prep_twf(
    const float* __restrict__ tw, _Float16* __restrict__ out, int CI, int KT)
{
  int g = blockIdx.x * 256 + threadIdx.x;
  int fid = g >> 6, lane = g & 63;
  int pl = fid & 1;
  int f2 = fid >> 1;
  int dt = f2 % 5;
  int f3 = f2 / 5;
  int ks = f3 & 1;
  int f4 = f3 >> 1;
  int kt = f4 % KT;
  int mt = f4 / KT;
  int m = mt * 32 + (lane & 31);
  int kb = kt * 32 + ks * 16 + ((lane >> 5) << 3);
  half8 o;
#pragma unroll
  for (int e = 0; e < 8; ++e) {
    float v = tw[((size_t)m * CI + (kb + e)) * 5 + dt];
    _Float16 h = (_Float16)v;
    o[e] = pl ? (_Float16)(v - (float)h) : h;
  }
  *(half8*)(out + ((size_t)fid * 64 + lane) * 8) = o;
}

// Pack gcn W_big = [Wg(3*COUT rows); Wr(COUT rows)] into fuse A-fragments.
__global__ __launch_bounds__(256) void k_pack_wz(
    const float* __restrict__ Wg, const float* __restrict__ Wr,
    _Float16* __restrict__ out, int CIN, int KT, int M3)
{
  int g = blockIdx.x * 256 + threadIdx.x;
  int fid = g >> 6, lane = g & 63;
  int pl = fid & 1;
  int ks = (fid >> 1) & 1;
  int rest = fid >> 2;
  int kt = rest % KT;
  int mt = rest / KT;
  int m = mt * 32 + (lane & 31);
  int kb = kt * 32 + ks * 16 + ((lane >> 5) << 3);
  const float* row = (m < M3) ? (Wg + (size_t)m * CIN) : (Wr + (size_t)(m - M3) * CIN);
  half8 o;
#pragma unroll
  for (int e = 0; e < 8; ++e) {
    float v = row[kb + e];
    _Float16 h = (_Float16)v;
    o[e] = pl ? (_Float16)(v - (float)h) : h;
  }
  *(half8*)(out + ((size_t)fid * 64 + lane) * 8) = o;
}

// ============================= layer 0 GCN (4 t per block) =============================
__global__ __launch_bounds__(256) void k_gcn0(
    const float* __restrict__ x,      // [B][T][24][3]
    const float* __restrict__ aeff,   // [3][24][24]
    const float* __restrict__ csum,   // [3][24]
    const float* __restrict__ dbg, const float* __restrict__ dbb,  // [72]
    const float* __restrict__ W0,     // [768][3]
    const float* __restrict__ gb0,    // [768]
    const float* __restrict__ g1, const float* __restrict__ b1,    // [256]
    _Float16* __restrict__ yh, _Float16* __restrict__ yl,          // [NBc][256]
    int b0)
{
  __shared__ float xbn[72];      // [cin][v]
  __shared__ float XA[216];      // [(k*3+ci)][w]
  __shared__ float WL[2304];
  __shared__ float tile[256 * 25];
  int t0 = blockIdx.x * 4, bl = blockIdx.y, tid = threadIdx.x;
  int b = b0 + bl;
  int c = tid;

  for (int i = tid; i < 2304; i += 256) WL[i] = W0[i];

  for (int tr = 0; tr < 4; ++tr) {
    int t = t0 + tr;
    __syncthreads();                 // WL ready (tr=0); xbn/tile free (tr>0)
    if (tid < 72) {
      int v = tid / 3, cin = tid % 3;
      float xv = x[(((size_t)b * gT + t) * gV + v) * 3 + cin];
      xbn[cin * 24 + v] = xv * (BN_INV * dbg[tid]) + dbb[tid];
    }
    __syncthreads();
    if (tid < 216) {
      int k = tid / 72, r = tid % 72, ci = r / 24, w = r % 24;
      const float* Ak = aeff + k * 576;
      float s = 0.f;
#pragma unroll
      for (int v = 0; v < 24; ++v) s += xbn[ci * 24 + v] * Ak[v * 24 + w];
      XA[tid] = s;
    }
    __syncthreads();

    float acc[24];
#pragma unroll
    for (int w = 0; w < 24; ++w) acc[w] = 0.f;
#pragma unroll
    for (int k = 0; k < 3; ++k) {
#pragma unroll
      for (int ci = 0; ci < 3; ++ci) {
        float wv = WL[(k * 256 + c) * 3 + ci];
#pragma unroll
        for (int w = 0; w < 24; ++w) acc[w] += wv * XA[(k * 3 + ci) * 24 + w];
      }
      float gv = gb0[k * 256 + c];
#pragma unroll
      for (int w = 0; w < 24; ++w) acc[w] += gv * csum[k * 24 + w];
    }
    float s1 = BN_INV * g1[c], o1 = b1[c];
#pragma unroll
    for (int w = 0; w < 24; ++w) tile[c * 25 + w] = fmaxf(acc[w] * s1 + o1, 0.f);
    __syncthreads();

    // vectorized plane writes: 8 c per thread, half8 (16B) stores; slab contiguous.
    size_t nb = ((size_t)bl * gN + (size_t)t * 24);
    _Float16* dhB = yh + nb * 256;
    _Float16* dlB = yl + nb * 256;
#pragma unroll
    for (int it = 0; it < 3; ++it) {
      int idx = it * 256 + tid;          // < 768 = 24 w * 32 c-octets
      int w = idx >> 5;
      int c0 = (idx & 31) * 8;
      half8 vh, vl;
#pragma unroll
      for (int q = 0; q < 8; ++q) {
        float v = tile[(c0 + q) * 25 + w];
        _Float16 hh = (_Float16)v;
        vh[q] = hh;
        vl[q] = (_Float16)(v - (float)hh);
      }
      *(half8*)(dhB + (size_t)w * 256 + c0) = vh;
      *(half8*)(dlB + (size_t)w * 256 + c0) = vl;
    }
  }
}

// ============================= fused gcn: Z-GEMM + A-contraction =============================
// B-staging now uses the tcn-proven pattern: XOR-swizzled 128B LDS rows, async
// global_load_lds (wave-uniform base), counted vmcnt dbuf (no halo, never OOB).
template <int CIN, int COUT>
__global__ __launch_bounds__(512) void k_gcnfuse(
    const _Float16* __restrict__ pH, const _Float16* __restrict__ pL, // [NBc][CIN]
    const _Float16* __restrict__ Wf,
    const float* __restrict__ aeffL, const float* __restrict__ csumL,
    const float* __restrict__ gb, const float* __restrict__ g1, const float* __restrict__ b1,
    _Float16* __restrict__ oH, _Float16* __restrict__ oL,  // [NBc][COUT]
    float* __restrict__ res_out,                           // [COUT][NBc] raw Z res rows
    int NBc)
{
  constexpr int KT = CIN / 32;
  constexpr int M = 4 * COUT;
  constexpr int M3 = 3 * COUT;
  constexpr int MT = M / 256;           // mt-tiles per wave (8 waves): L1: 2, L2: 1
  constexpr int NSLOT = 96 * 8;                 // 16B slots per buffer (768)
  constexpr int BSTG_FL = 2 * NSLOT * 4;        // dbuf staging floats (6144)
  constexpr int ZLW = M * 25;                   // ZL floats (L1: 12800, L2: 6400)
  constexpr int UNIW = (ZLW > BSTG_FL) ? ZLW : BSTG_FL;
  __shared__ float UNI[UNIW];
  __shared__ float AL[1728];
  __shared__ float csL[72];
  __shared__ __align__(16) _Float16 YST[24 * COUT * 2];  // staged y slab: hi | lo planes
  _Float16* Bb = (_Float16*)UNI;
  float* ZL = UNI;

  int tid = threadIdx.x, w = tid >> 6, lane = tid & 63;
  int n0 = blockIdx.x * 96;

  for (int i = tid; i < 1728; i += 512) AL[i] = aeffL[i];
  if (tid < 72) csL[tid] = csumL[tid];

  floatx16 acc[MT][3] = {};

  // slot s at row r holds source (pl,seg) = decompose(s ^ (r & 7)); row = n-local.
  auto ISSUE = [&](int kt, int buf) {
#pragma unroll
    for (int it = 0; it < 2; ++it) {
      int base = it * 512 + w * 64;        // wave-uniform slot base
      if (base < NSLOT) {
        int T = base + lane;
        int r = T >> 3, s = T & 7;
        int sl = s ^ (r & 7);
        int pl = sl >> 2, seg = sl & 3;
        const _Float16* src = (pl ? pL : pH) + (size_t)(n0 + r) * CIN + kt * 32 + seg * 8;
        GLOAD_LDS16(src, Bb + ((size_t)buf * NSLOT + base) * 8);
      }
    }
  };
  auto COMPUTE = [&](int kt, int buf) {
    const _Float16* B = Bb + (size_t)buf * NSLOT * 8;
    __builtin_amdgcn_s_setprio(1);
#pragma unroll
    for (int ks = 0; ks < 2; ++ks) {
      int seg = ks * 2 + (lane >> 5);
      half8 bh[3], bl[3];
#pragma unroll
      for (int nf = 0; nf < 3; ++nf) {
        int rr = (lane & 31) + nf * 32;
        bh[nf] = *(const half8*)(B + rr * 64 + (((0 + seg) ^ (rr & 7)) * 8));
        bl[nf] = *(const half8*)(B + rr * 64 + (((4 + seg) ^ (rr & 7)) * 8));
      }
#pragma unroll
      for (int mti = 0; mti < MT; ++mti) {
        int mt = w * MT + mti;
        int fid = ((mt * KT + kt) * 2 + ks) * 2;
        half8 ah = *(const half8*)(Wf + ((size_t)fid * 64 + lane) * 8);
        half8 al = *(const half8*)(Wf + ((size_t)(fid + 1) * 64 + lane) * 8);
#pragma unroll
        for (int nf = 0; nf < 3; ++nf) {
          acc[mti][nf] = __builtin_amdgcn_mfma_f32_32x32x16_f16(ah, bh[nf], acc[mti][nf], 0, 0, 0);
          acc[mti][nf] = __builtin_amdgcn_mfma_f32_32x32x16_f16(ah, bl[nf], acc[mti][nf], 0, 0, 0);
          acc[mti][nf] = __builtin_amdgcn_mfma_f32_32x32x16_f16(al, bh[nf], acc[mti][nf], 0, 0, 0);
        }
      }
    }
    __builtin_amdgcn_s_setprio(0);
  };

  ISSUE(0, 0);
  int cur = 0;
  for (int kt = 0; kt < KT; ++kt) {
    __builtin_amdgcn_sched_barrier(0);
    if (kt + 1 < KT) ISSUE(kt + 1, cur ^ 1);
    __builtin_amdgcn_sched_barrier(0);
    if (kt + 1 < KT) {
      // waves 0-3 just issued 2 loads, waves 4-7 issued 1 -> leave only those in flight
      if (w < 4) asm volatile("s_waitcnt vmcnt(2)" ::: "memory");
      else       asm volatile("s_waitcnt vmcnt(1)" ::: "memory");
    } else {
      asm volatile("s_waitcnt vmcnt(0)" ::: "memory");
    }
    __builtin_amdgcn_sched_barrier(0);
    __builtin_amdgcn_s_barrier();
    __builtin_amdgcn_sched_barrier(0);
    COMPUTE(kt, cur);
    asm volatile("s_waitcnt lgkmcnt(0)" ::: "memory");
    __builtin_amdgcn_sched_barrier(0);
    __builtin_amdgcn_s_barrier();
    cur ^= 1;
  }

  constexpr int SUBS = 512 / COUT;     // L1: 4, L2: 8
  constexpr int WR = 24 / SUBS;        // L1: 6, L2: 3
  int c = tid & (COUT - 1);
  int w0 = (tid / COUT) * WR;
  float s1 = BN_INV * g1[c], o1 = b1[c];
  float gv0 = gb[c], gv1 = gb[COUT + c], gv2 = gb[2 * COUT + c];

  for (int tr = 0; tr < 4; ++tr) {
    __syncthreads();
#pragma unroll
    for (int mti = 0; mti < MT; ++mti) {
#pragma unroll
      for (int nf = 0; nf < 3; ++nf) {
        int nloc = nf * 32 + (lane & 31) - tr * 24;
        if (nloc >= 0 && nloc < 24) {
          int mb_ = (w * MT + mti) * 32 + 4 * (lane >> 5);
#pragma unroll
          for (int r = 0; r < 16; ++r)
            ZL[(mb_ + (r & 3) + 8 * (r >> 2)) * 25 + nloc] = acc[mti][nf][r];
        }
      }
    }
    __syncthreads();
    float y[WR];
#pragma unroll
    for (int j = 0; j < WR; ++j) y[j] = 0.f;
#pragma unroll
    for (int k = 0; k < 3; ++k) {
#pragma unroll
      for (int v = 0; v < 24; ++v) {
        float zr = ZL[(k * COUT + c) * 25 + v];
        const float* ap = &AL[k * 576 + v * 24 + w0];
#pragma unroll
        for (int j = 0; j < WR; ++j) y[j] += zr * ap[j];
      }
    }
#pragma unroll
    for (int j = 0; j < WR; ++j) {
      int ww = w0 + j;
      float bias = gv0 * csL[ww] + gv1 * csL[24 + ww] + gv2 * csL[48 + ww];
      float yv = fmaxf((y[j] + bias) * s1 + o1, 0.f);
      _Float16 h = (_Float16)yv;
      YST[ww * COUT + c] = h;
      YST[24 * COUT + ww * COUT + c] = (_Float16)(yv - (float)h);
    }
    __syncthreads();
    // bulk 16B plane writes (slab contiguous in global) + float4 res writes
    constexpr int QT = 24 * COUT / 8;        // half8 per plane
    size_t nbase = (size_t)n0 + tr * 24;
    for (int idx = tid; idx < 2 * QT; idx += 512) {
      int plane = idx / QT, q = idx - plane * QT;
      _Float16* dst = (plane ? oL : oH) + nbase * COUT + q * 8;
      *(half8*)dst = *(half8*)(YST + plane * 24 * COUT + q * 8);
    }
    for (int idx = tid; idx < COUT * 6; idx += 512) {
      int cc = idx / 6, q = idx - cc * 6;
      float4 v4;
      v4.x = ZL[(M3 + cc) * 25 + 4 * q + 0];
      v4.y = ZL[(M3 + cc) * 25 + 4 * q + 1];
      v4.z = ZL[(M3 + cc) * 25 + 4 * q + 2];
      v4.w = ZL[(M3 + cc) * 25 + 4 * q + 3];
      *(float4*)(res_out + (size_t)cc * NBc + nbase + 4 * q) = v4;
    }
  }
}

// ============================= temporal conv (MFMA, 512 threads / 8 waves) =============================
// Block covers full M=CIO; waves tile (wm,wn) over M x 128-col N. Counted-vmcnt dbuf.
// FUSE_FC: apply fc to post-relu h in-register, reduce, write d_out directly.
template <int CIO, int MF, bool FUSE_FC>
__global__ __launch_bounds__(512) void k_tcn_mfma(
    const _Float16* __restrict__ yH, const _Float16* __restrict__ yL, // [NBc][CIO]
    const _Float16* __restrict__ Apack,
    const float* __restrict__ tb, const float* __restrict__ g2, const float* __restrict__ b2,
    const float* __restrict__ Zres,   // res rows [CIO][NBc] raw, or nullptr
    const float* __restrict__ rb, const float* __restrict__ rg, const float* __restrict__ rbb,
    _Float16* __restrict__ oH, _Float16* __restrict__ oL,  // [NBc][CIO] (unused if FUSE_FC)
    const float* __restrict__ fw, const float* __restrict__ fb,  // fc params (FUSE_FC)
    float* __restrict__ outp, int b0,
    int NBc)
{
  constexpr int KT = CIO / 32;
  constexpr int M = CIO;
  constexpr int NWAVE_M = M / (MF * 32);      // 256:4  128:2  64:2
  constexpr int NWAVE_N = 8 / NWAVE_M;        // 256:2  128:4  64:4
  constexpr int NF = 128 / (32 * NWAVE_N);    // 256:2  128:1  64:1
  constexpr int NROW = 224;                   // 128 cols + 96 halo rows
  __shared__ _Float16 Bt[2][NROW * 64];       // 2 x 28672 B
  __shared__ float scL[CIO], ofL[CIO], tbL[CIO], rscL[CIO], rofL[CIO], rbvL[CIO];
  __shared__ float fwL[FUSE_FC ? 384 : 4];
  int bx = blockIdx.x, bl = blockIdx.z;
  int tid = threadIdx.x, w = tid >> 6, lane = tid & 63;
  int wn = w % NWAVE_N, wm = w / NWAVE_N;
  int n0 = bx * 128;
  bool interior = (bx > 0) && (bx < 47);

  for (int i = tid; i < CIO; i += 512) {
    scL[i] = BN_INV * g2[i]; ofL[i] = b2[i]; tbL[i] = tb[i];
    if (Zres) { rscL[i] = BN_INV * rg[i]; rofL[i] = rbb[i]; rbvL[i] = rb[i]; }
  }
  if (FUSE_FC) { for (int i = tid; i < 384; i += 512) fwL[i] = fw[i]; }

  floatx16 acc[MF][NF] = {};
  const _Float16* ybH = yH + (size_t)bl * gN * CIO;
  const _Float16* ybL = yL + (size_t)bl * gN * CIO;
  int mt_base = wm * MF;

  auto ISSUE = [&](int kt, int buf) {   // async gload_lds; slots w*4+it, 28 used
#pragma unroll
    for (int it = 0; it < 4; ++it) {
      int slot = w * 4 + it;
      if (slot < 28) {
        int T = slot * 64 + lane;
        int r = T >> 3, s = T & 7;
        int sl = s ^ (r & 7);
        int pl = sl >> 2, seg = sl & 3;
        int n = n0 - 48 + r;
        const _Float16* src = (pl ? ybL : ybH) + (size_t)n * CIO + kt * 32 + seg * 8;
        GLOAD_LDS16(src, &Bt[buf][(size_t)slot * 512]);
      }
    }
  };
  auto ISSUE_EDGE = [&](int kt, int buf) {  // reg-staged, zero-filled halo
#pragma unroll
    for (int it = 0; it < 4; ++it) {
      int slot = w * 4 + it;
      if (slot < 28) {
        int T = slot * 64 + lane;
        int r = T >> 3, s = T & 7;
        int sl = s ^ (r & 7);
        int pl = sl >> 2, seg = sl & 3;
        int n = n0 - 48 + r;
        uint4 vv = make_uint4(0u, 0u, 0u, 0u);
        if (n >= 0 && n < gN)
          vv = *(const uint4*)((pl ? ybL : ybH) + (size_t)n * CIO + kt * 32 + seg * 8);
        *(uint4*)(&Bt[buf][(size_t)T * 8]) = vv;
      }
    }
  };
  auto COMPUTE = [&](int kt, int buf) {
    const _Float16* B = &Bt[buf][0];
    __builtin_amdgcn_s_setprio(1);
#pragma unroll
    for (int dt = 0; dt < 5; ++dt) {
#pragma unroll
      for (int ks = 0; ks < 2; ++ks) {
        int seg = ks * 2 + (lane >> 5);
        half8 bh[NF], blv[NF];
#pragma unroll
        for (int nf = 0; nf < NF; ++nf) {
          int rr = wn * (NF * 32) + nf * 32 + dt * 24 + (lane & 31);
          bh[nf]  = *(const half8*)(B + rr * 64 + (((0 + seg) ^ (rr & 7)) * 8));
          blv[nf] = *(const half8*)(B + rr * 64 + (((4 + seg) ^ (rr & 7)) * 8));
        }
#pragma unroll
        for (int mf = 0; mf < MF; ++mf) {
          int fid = ((((mt_base + mf) * KT + kt) * 2 + ks) * 5 + dt) * 2;
          half8 ah = *(const half8*)(Apack + ((size_t)fid * 64 + lane) * 8);
          half8 al = *(const half8*)(Apack + ((size_t)(fid + 1) * 64 + lane) * 8);
#pragma unroll
          for (int nf = 0; nf < NF; ++nf) {
            acc[mf][nf] = __builtin_amdgcn_mfma_f32_32x32x16_f16(ah, bh[nf], acc[mf][nf], 0, 0, 0);
            acc[mf][nf] = __builtin_amdgcn_mfma_f32_32x32x16_f16(ah, blv[nf], acc[mf][nf], 0, 0, 0);
            acc[mf][nf] = __builtin_amdgcn_mfma_f32_32x32x16_f16(al, bh[nf], acc[mf][nf], 0, 0, 0);
          }
        }
      }
    }
    __builtin_amdgcn_s_setprio(0);
  };

  if (interior) {
    ISSUE(0, 0);
    int cur = 0;
    for (int kt = 0; kt < KT; ++kt) {
      __builtin_amdgcn_sched_barrier(0);
      if (kt + 1 < KT) ISSUE(kt + 1, cur ^ 1);
      __builtin_amdgcn_sched_barrier(0);
      if (kt + 1 < KT) asm volatile("s_waitcnt vmcnt(4)" ::: "memory");
      else             asm volatile("s_waitcnt vmcnt(0)" ::: "memory");
      __builtin_amdgcn_sched_barrier(0);
      __builtin_amdgcn_s_barrier();
      __builtin_amdgcn_sched_barrier(0);
      COMPUTE(kt, cur);
      asm volatile("s_waitcnt lgkmcnt(0)" ::: "memory");
      __builtin_amdgcn_sched_barrier(0);
      __builtin_amdgcn_s_barrier();
      cur ^= 1;
    }
  } else {
    for (int kt = 0; kt < KT; ++kt) {
      __syncthreads();
      ISSUE_EDGE(kt, 0);
      __syncthreads();
      COMPUTE(kt, 0);
    }
  }

  // epilogue: acc -> z (bias + bn2 + res + relu), in place
  int blgN = bl * gN;
#pragma unroll
  for (int mf = 0; mf < MF; ++mf) {
    int m32 = wm * MF * 32 + mf * 32 + 4 * (lane >> 5);
#pragma unroll
    for (int nf = 0; nf < NF; ++nf) {
      int n = n0 + wn * (NF * 32) + nf * 32 + (lane & 31);
      size_t nflat = (size_t)blgN + n;
#pragma unroll
      for (int r = 0; r < 16; ++r) {
        int co = m32 + (r & 3) + 8 * (r >> 2);
        float z = (acc[mf][nf][r] + tbL[co]) * scL[co] + ofL[co];
        if (Zres) z += (Zres[(size_t)co * NBc + nflat] + rbvL[co]) * rscL[co] + rofL[co];
        acc[mf][nf][r] = fmaxf(z, 0.f);
      }
    }
  }

  if constexpr (FUSE_FC) {
    // MF=1, NF=1, NWAVE_M=2 (wm 0..1), NWAVE_N=4 (wn 0..3).
    __syncthreads();                   // Bt free
    float* FC = (float*)&Bt[0][0];     // [2 wm][128 n][6]
    float p[6];
#pragma unroll
    for (int o = 0; o < 6; ++o) p[o] = 0.f;
    int m32 = wm * 32 + 4 * (lane >> 5);
#pragma unroll
    for (int r = 0; r < 16; ++r) {
      int co = m32 + (r & 3) + 8 * (r >> 2);
      float z = acc[0][0][r];
#pragma unroll
      for (int o = 0; o < 6; ++o) p[o] += fwL[o * 64 + co] * z;
    }
#pragma unroll
    for (int o = 0; o < 6; ++o) p[o] += __shfl_xor(p[o], 32);
    if (lane < 32) {
      int nloc = wn * 32 + lane;
#pragma unroll
      for (int o = 0; o < 6; ++o)
        FC[(wm * 128 + nloc) * 6 + o] = p[o];
    }
    __syncthreads();
    for (int idx = tid; idx < 768; idx += 512) {
      int nloc = idx / 6, o = idx % 6;
      float val = fb[o] + FC[nloc * 6 + o] + FC[(128 + nloc) * 6 + o];
      int n = n0 + nloc;
      int t = n / 24, v = n % 24;
      outp[(((size_t)(b0 + bl) * gT + t) * gV + v) * 6 + o] = val;
    }
  } else {
    // LDS-transpose + 16B plane writes.  ST rows per pass chosen to fit Bt.
    constexpr int CPB = CIO / 2;       // co-pair dwords per n-row
    constexpr int NHALF = (128 * (CPB + 1) * 4 > 2 * NROW * 64 * 2) ? 2 : 1;
    constexpr int ROWS_P = 128 / NHALF;
    constexpr int PITCH = CPB + 1;
    uint* ST = (uint*)&Bt[0][0];
    uint* oH32 = (uint*)oH;
    uint* oL32 = (uint*)oL;
    constexpr int QITERS = ROWS_P * CPB / 4 / 512;

#pragma unroll
    for (int half = 0; half < NHALF; ++half) {
#pragma unroll
      for (int pass = 0; pass < 2; ++pass) {
        __syncthreads();
        if (NHALF == 1 || wn == half) {
          int cl = wm * MF * 32;
#pragma unroll
          for (int mf = 0; mf < MF; ++mf) {
#pragma unroll
            for (int nf = 0; nf < NF; ++nf) {
              int nl = wn * (NF * 32) + nf * 32 + (lane & 31) - half * ROWS_P;
#pragma unroll
              for (int r = 0; r < 16; r += 2) {
                float z0 = acc[mf][nf][r], z1 = acc[mf][nf][r + 1];
                _Float16 a0 = (_Float16)z0, a1 = (_Float16)z1;
                if (pass == 1) { a0 = (_Float16)(z0 - (float)a0); a1 = (_Float16)(z1 - (float)a1); }
                half2v p2; p2[0] = a0; p2[1] = a1;
                int col2 = (cl + mf * 32 + 4 * (lane >> 5) + (r & 3) + 8 * (r >> 2)) >> 1;
                ST[nl * PITCH + col2] = *(uint*)&p2;
              }
            }
          }
        }
        __syncthreads();
        uint* dst = (pass == 0) ? oH32 : oL32;
#pragma unroll
        for (int i = 0; i < QITERS; ++i) {
          int idx = i * 512 + tid;                    // quad id
          int row = idx / (CPB / 4), c4 = (idx % (CPB / 4)) * 4;
          uint4 v;
          v.x = ST[row * PITCH + c4 + 0];
          v.y = ST[row * PITCH + c4 + 1];
          v.z = ST[row * PITCH + c4 + 2];
          v.w = ST[row * PITCH + c4 + 3];
          *(uint4*)(dst + ((size_t)blgN + n0 + half * ROWS_P + row) * (CIO / 2) + c4) = v;
        }
      }
    }
  }
}

// ============================= host =============================
extern "C" void kernel_launch(void* const* d_in, const int* in_sizes, int n_in,
                              void* d_out, int out_size, void* d_ws, size_t ws_size,
                              hipStream_t stream) {
  const float* x    = (const float*)d_in[0];
  const float* A    = (const float*)d_in[1];
  const float* dbg  = (const float*)d_in[2];
  const float* dbb  = (const float*)d_in[3];
  const float* ei0  = (const float*)d_in[4];
  const float* ei1  = (const float*)d_in[5];
  const float* ei2  = (const float*)d_in[6];
  const float* w0g  = (const float*)d_in[7];
  const float* gb0  = (const float*)d_in[8];
  const float* g10  = (const float*)d_in[9];
  const float* b10  = (const float*)d_in[10];
  const float* tw0  = (const float*)d_in[11];
  const float* tb0  = (const float*)d_in[12];
  const float* g20  = (const float*)d_in[13];
  const float* b20  = (const float*)d_in[14];
  const float* w1g  = (const float*)d_in[15];
  const float* gb1  = (const float*)d_in[16];
  const float* g11  = (const float*)d_in[17];
  const float* b11  = (const float*)d_in[18];
  const float* tw1  = (const float*)d_in[19];
  const float* tb1  = (const float*)d_in[20];
  const float* g21  = (const float*)d_in[21];
  const float* b21  = (const float*)d_in[22];
  const float* rw1  = (const float*)d_in[23];
  const float* rb1  = (const float*)d_in[24];
  const float* rg1  = (const float*)d_in[25];
  const float* rbb1 = (const float*)d_in[26];
  const float* w2g  = (const float*)d_in[27];
  const float* gb2  = (const float*)d_in[28];
  const float* g12  = (const float*)d_in[29];
  const float* b12  = (const float*)d_in[30];
  const float* tw2  = (const float*)d_in[31];
  const float* tb2  = (const float*)d_in[32];
  const float* g22  = (const float*)d_in[33];
  const float* b22  = (const float*)d_in[34];
  const float* rw2  = (const float*)d_in[35];
  const float* rb2  = (const float*)d_in[36];
  const float* rg2  = (const float*)d_in[37];
  const float* rbb2 = (const float*)d_in[38];
  const float* fw   = (const float*)d_in[39];
  const float* fb   = (const float*)d_in[40];
  float* outp = (float*)d_out;
  float* ws = (float*)d_ws;

  // ws layout (floats)
  size_t off = 0;
  auto alloc = [&](size_t n) { size_t o = off; off += n; return o; };
  size_t oAE  = alloc(3 * 1728);
  size_t oCS  = alloc(3 * 72);
  size_t oA0  = alloc((size_t)1280 * 512 / 2);  // tcn0 frags
  size_t oA1  = alloc((size_t)320 * 512 / 2);
  size_t oA2  = alloc((size_t)80 * 512 / 2);
  size_t oWz1 = alloc((size_t)512 * 512 / 2);   // 512 frags * 512 halves
  size_t oWz2 = alloc((size_t)128 * 512 / 2);
  off = (off + 3) & ~(size_t)3;

  // per batch (floats/n): planes buf1 256 + planes buf2 256 + res rows 128 = 640
  const size_t perBatchBytes = (size_t)gN * 640 * 4;   // 15.73 MB
  int Bc = 32;
  while (Bc > 1 && off * 4 + (size_t)Bc * perBatchBytes > ws_size) Bc >>= 1;
  int NBc = Bc * gN;

  float* B1 = ws + off;
  float* B2 = B1 + (size_t)NBc * 256;
  float* Rb = B2 + (size_t)NBc * 256;          // res rows [<=128][NBc]
  _Float16* b1h = (_Float16*)B1;
  _Float16* b2h = (_Float16*)B2;
  _Float16* A0 = (_Float16*)(ws + oA0);
  _Float16* A1 = (_Float16*)(ws + oA1);
  _Float16* A2 = (_Float16*)(ws + oA2);
  _Float16* Wz1 = (_Float16*)(ws + oWz1);
  _Float16* Wz2 = (_Float16*)(ws + oWz2);

  // ---- prep ----
  k_prep_aeff<<<21, 256, 0, stream>>>(A, ei0, ei1, ei2, ws + oAE, ws + oCS);
  k_prep_twf<<<320, 256, 0, stream>>>(tw0, A0, 256, 8);
  k_prep_twf<<<80, 256, 0, stream>>>(tw1, A1, 128, 4);
  k_prep_twf<<<20, 256, 0, stream>>>(tw2, A2, 64, 2);
  k_pack_wz<<<128, 256, 0, stream>>>(w1g, rw1, Wz1, 256, 8, 384);  // M=512,K=256
  k_pack_wz<<<32, 256, 0, stream>>>(w2g, rw2, Wz2, 128, 4, 192);   // M=256,K=128

  for (int b0 = 0; b0 < 32; b0 += Bc) {
    // layer 0: gcn0 -> P1(256); tcn0 -> P2(256)
    k_gcn0<<<dim3(gT / 4, Bc), 256, 0, stream>>>(x, ws + oAE, ws + oCS, dbg, dbb,
                                                 w0g, gb0, g10, b10,
                                                 b1h, b1h + (size_t)NBc * 256, b0);
    k_tcn_mfma<256, 2, false><<<dim3(48, 1, Bc), 512, 0, stream>>>(
        b1h, b1h + (size_t)NBc * 256, A0, tb0, g20, b20,
        nullptr, nullptr, nullptr, nullptr,
        b2h, b2h + (size_t)NBc * 256, nullptr, nullptr, nullptr, 0, NBc);
    // layer 1: fused gcn (P2 -> P1 planes + res rows); tcn1(P1 + res) -> P2
    k_gcnfuse<256, 128><<<dim3(NBc / 96), 512, 0, stream>>>(
        b2h, b2h + (size_t)NBc * 256, Wz1,
        ws + oAE + 1728, ws + oCS + 72, gb1, g11, b11,
        b1h, b1h + (size_t)NBc * 128, Rb, NBc);
    k_tcn_mfma<128, 2, false><<<dim3(48, 1, Bc), 512, 0, stream>>>(
        b1h, b1h + (size_t)NBc * 128, A1, tb1, g21, b21,
        Rb, rb1, rg1, rbb1,
        b2h, b2h + (size_t)NBc * 128, nullptr, nullptr, nullptr, 0, NBc);
    // layer 2
    k_gcnfuse<128, 64><<<dim3(NBc / 96), 512, 0, stream>>>(
        b2h, b2h + (size_t)NBc * 128, Wz2,
        ws + oAE + 2 * 1728, ws + oCS + 144, gb2, g12, b12,
        b1h, b1h + (size_t)NBc * 64, Rb, NBc);
    // tcn2 + fused fc -> d_out directly
    k_tcn_mfma<64, 1, true><<<dim3(48, 1, Bc), 512, 0, stream>>>(
        b1h, b1h + (size_t)NBc * 64, A2, tb2, g22, b22,
        Rb, rb2, rg2, rbb2,
        nullptr, nullptr, fw, fb, outp, b0, NBc);
  }
  (void)in_sizes; (void)n_in; (void)out_size;
}

// Round 22
// 1242.625 us; speedup vs baseline: 1.3238x; 1.0050x over previous
//
#include <hip/hip_runtime.h>

typedef _Float16 half8 __attribute__((ext_vector_type(8)));
typedef _Float16 half2v __attribute__((ext_vector_type(2)));
typedef float floatx16 __attribute__((ext_vector_type(16)));

static constexpr int gT = 256;      // time steps
static constexpr int gV = 24;       // graph nodes
static constexpr int gN = gT * gV;  // 6144 columns per batch
static constexpr float BN_INV = 0.99999500003749969f; // 1/sqrt(1+1e-5)

#define GLOAD_LDS16(g, l)                                            \
  __builtin_amdgcn_global_load_lds(                                  \
      (const __attribute__((address_space(1))) unsigned int*)(g),    \
      (__attribute__((address_space(3))) unsigned int*)(l), 16, 0, 0)

// ============================= prep kernels =============================
__global__ __launch_bounds__(256) void k_prep_aeff(
    const float* __restrict__ A, const float* __restrict__ e0,
    const float* __restrict__ e1, const float* __restrict__ e2,
    float* __restrict__ aeff, float* __restrict__ csum)
{
  int tid = blockIdx.x * 256 + threadIdx.x;
  if (tid < 3 * 1728) {
    int l = tid / 1728, r = tid % 1728;
    const float* e = (l == 0) ? e0 : ((l == 1) ? e1 : e2);
    aeff[tid] = A[r] * e[r];
  }
  if (tid < 3 * 72) {
    int l = tid / 72, r = tid % 72;
    int k = r / 24, w = r % 24;
    const float* e = (l == 0) ? e0 : ((l == 1) ? e1 : e2);
    float s = 0.f;
    for (int v = 0; v < 24; ++v) { int idx = (k * 24 + v) * 24 + w; s += A[idx] * e[idx]; }
    csum[tid] = s;
  }
}

// Pack tcn weights into MFMA A-fragment order, f16 hi/lo split.
__global__ __launch_bounds__(256) void k_prep_twf(
    const float* __restrict__ tw, _Float16* __restrict__ out, int CI, int KT)
{
  int g = blockIdx.x * 256 + threadIdx.x;
  int fid = g >> 6, lane = g & 63;
  int pl = fid & 1;
  int f2 = fid >> 1;
  int dt = f2 % 5;
  int f3 = f2 / 5;
  int ks = f3 & 1;
  int f4 = f3 >> 1;
  int kt = f4 % KT;
  int mt = f4 / KT;
  int m = mt * 32 + (lane & 31);
  int kb = kt * 32 + ks * 16 + ((lane >> 5) << 3);
  half8 o;
#pragma unroll
  for (int e = 0; e < 8; ++e) {
    float v = tw[((size_t)m * CI + (kb + e)) * 5 + dt];
    _Float16 h = (_Float16)v;
    o[e] = pl ? (_Float16)(v - (float)h) : h;
  }
  *(half8*)(out + ((size_t)fid * 64 + lane) * 8) = o;
}

// Pack gcn W_big = [Wg(3*COUT rows); Wr(COUT rows)] into fuse A-fragments.
__global__ __launch_bounds__(256) void k_pack_wz(
    const float* __restrict__ Wg, const float* __restrict__ Wr,
    _Float16* __restrict__ out, int CIN, int KT, int M3)
{
  int g = blockIdx.x * 256 + threadIdx.x;
  int fid = g >> 6, lane = g & 63;
  int pl = fid & 1;
  int ks = (fid >> 1) & 1;
  int rest = fid >> 2;
  int kt = rest % KT;
  int mt = rest / KT;
  int m = mt * 32 + (lane & 31);
  int kb = kt * 32 + ks * 16 + ((lane >> 5) << 3);
  const float* row = (m < M3) ? (Wg + (size_t)m * CIN) : (Wr + (size_t)(m - M3) * CIN);
  half8 o;
#pragma unroll
  for (int e = 0; e < 8; ++e) {
    float v = row[kb + e];
    _Float16 h = (_Float16)v;
    o[e] = pl ? (_Float16)(v - (float)h) : h;
  }
  *(half8*)(out + ((size_t)fid * 64 + lane) * 8) = o;
}

// ============================= layer 0 GCN (4 t per block, batched phases) ==========
__global__ __launch_bounds__(256) void k_gcn0(
    const float* __restrict__ x,      // [B][T][24][3]
    const float* __restrict__ aeff,   // [3][24][24]
    const float* __restrict__ csum,   // [3][24]
    const float* __restrict__ dbg, const float* __restrict__ dbb,  // [72]
    const float* __restrict__ W0,     // [768][3]
    const float* __restrict__ gb0,    // [768]
    const float* __restrict__ g1, const float* __restrict__ b1,    // [256]
    _Float16* __restrict__ yh, _Float16* __restrict__ yl,          // [NBc][256]
    int b0)
{
  __shared__ float xbn4[288];    // [tr][cin*24+v]
  __shared__ float XA4[864];     // [tr][(k*3+ci)*24+w]
  __shared__ float WL[2304];
  __shared__ float tile[256 * 25];
  int t0 = blockIdx.x * 4, bl = blockIdx.y, tid = threadIdx.x;
  int b = b0 + bl;
  int c = tid;

  for (int i = tid; i < 2304; i += 256) WL[i] = W0[i];
  for (int i = tid; i < 288; i += 256) {
    int tr = i / 72, r = i % 72;
    int v = r / 3, cin = r % 3;
    float xv = x[(((size_t)b * gT + (t0 + tr)) * gV + v) * 3 + cin];
    xbn4[tr * 72 + cin * 24 + v] = xv * (BN_INV * dbg[r]) + dbb[r];
  }
  __syncthreads();

  for (int i = tid; i < 864; i += 256) {
    int tr = i / 216, rr = i % 216;
    int k = rr / 72, r2 = rr % 72, ci = r2 / 24, w = rr % 24;
    const float* Ak = aeff + k * 576;
    const float* xb = &xbn4[tr * 72 + ci * 24];
    float s = 0.f;
#pragma unroll
    for (int v = 0; v < 24; ++v) s += xb[v] * Ak[v * 24 + w];
    XA4[tr * 216 + rr] = s;
  }
  __syncthreads();

  float s1 = BN_INV * g1[c], o1 = b1[c];
  float gv0 = gb0[c], gv1 = gb0[256 + c], gv2 = gb0[512 + c];
  float wv9[9];
#pragma unroll
  for (int k = 0; k < 3; ++k)
#pragma unroll
    for (int ci = 0; ci < 3; ++ci) wv9[k * 3 + ci] = WL[(k * 256 + c) * 3 + ci];

  for (int tr = 0; tr < 4; ++tr) {
    int t = t0 + tr;
    float acc[24];
#pragma unroll
    for (int w = 0; w < 24; ++w) acc[w] = 0.f;
    const float* XAt = &XA4[tr * 216];
#pragma unroll
    for (int k = 0; k < 3; ++k) {
#pragma unroll
      for (int ci = 0; ci < 3; ++ci) {
        float wv = wv9[k * 3 + ci];
#pragma unroll
        for (int w = 0; w < 24; ++w) acc[w] += wv * XAt[(k * 3 + ci) * 24 + w];
      }
      float gv = (k == 0) ? gv0 : ((k == 1) ? gv1 : gv2);
#pragma unroll
      for (int w = 0; w < 24; ++w) acc[w] += gv * csum[k * 24 + w];
    }
#pragma unroll
    for (int w = 0; w < 24; ++w) tile[c * 25 + w] = fmaxf(acc[w] * s1 + o1, 0.f);
    __syncthreads();

    // vectorized plane writes: 8 c per thread, half8 (16B) stores; slab contiguous.
    size_t nb = ((size_t)bl * gN + (size_t)t * 24);
    _Float16* dhB = yh + nb * 256;
    _Float16* dlB = yl + nb * 256;
#pragma unroll
    for (int it = 0; it < 3; ++it) {
      int idx = it * 256 + tid;          // < 768 = 24 w * 32 c-octets
      int w = idx >> 5;
      int c0 = (idx & 31) * 8;
      half8 vh, vl;
#pragma unroll
      for (int q = 0; q < 8; ++q) {
        float v = tile[(c0 + q) * 25 + w];
        _Float16 hh = (_Float16)v;
        vh[q] = hh;
        vl[q] = (_Float16)(v - (float)hh);
      }
      *(half8*)(dhB + (size_t)w * 256 + c0) = vh;
      *(half8*)(dlB + (size_t)w * 256 + c0) = vl;
    }
    __syncthreads();                 // tile reused next tr
  }
}

// ============================= fused gcn: Z-GEMM + A-contraction =============================
// B-staging uses the tcn-proven pattern: XOR-swizzled 128B LDS rows, async
// global_load_lds (wave-uniform base), counted vmcnt dbuf (no halo, never OOB).
template <int CIN, int COUT>
__global__ __launch_bounds__(512) void k_gcnfuse(
    const _Float16* __restrict__ pH, const _Float16* __restrict__ pL, // [NBc][CIN]
    const _Float16* __restrict__ Wf,
    const float* __restrict__ aeffL, const float* __restrict__ csumL,
    const float* __restrict__ gb, const float* __restrict__ g1, const float* __restrict__ b1,
    _Float16* __restrict__ oH, _Float16* __restrict__ oL,  // [NBc][COUT]
    float* __restrict__ res_out,                           // [COUT][NBc] raw Z res rows
    int NBc)
{
  constexpr int KT = CIN / 32;
  constexpr int M = 4 * COUT;
  constexpr int M3 = 3 * COUT;
  constexpr int MT = M / 256;           // mt-tiles per wave (8 waves): L1: 2, L2: 1
  constexpr int NSLOT = 96 * 8;                 // 16B slots per buffer (768)
  constexpr int BSTG_FL = 2 * NSLOT * 4;        // dbuf staging floats (6144)
  constexpr int ZLW = M * 25;                   // ZL floats (L1: 12800, L2: 6400)
  constexpr int UNIW = (ZLW > BSTG_FL) ? ZLW : BSTG_FL;
  __shared__ float UNI[UNIW];
  __shared__ float AL[1728];
  __shared__ float csL[72];
  __shared__ __align__(16) _Float16 YST[24 * COUT * 2];  // staged y slab: hi | lo planes
  _Float16* Bb = (_Float16*)UNI;
  float* ZL = UNI;

  int tid = threadIdx.x, w = tid >> 6, lane = tid & 63;
  int n0 = blockIdx.x * 96;

  for (int i = tid; i < 1728; i += 512) AL[i] = aeffL[i];
  if (tid < 72) csL[tid] = csumL[tid];

  floatx16 acc[MT][3] = {};

  // slot s at row r holds source (pl,seg) = decompose(s ^ (r & 7)); row = n-local.
  auto ISSUE = [&](int kt, int buf) {
#pragma unroll
    for (int it = 0; it < 2; ++it) {
      int base = it * 512 + w * 64;        // wave-uniform slot base
      if (base < NSLOT) {
        int T = base + lane;
        int r = T >> 3, s = T & 7;
        int sl = s ^ (r & 7);
        int pl = sl >> 2, seg = sl & 3;
        const _Float16* src = (pl ? pL : pH) + (size_t)(n0 + r) * CIN + kt * 32 + seg * 8;
        GLOAD_LDS16(src, Bb + ((size_t)buf * NSLOT + base) * 8);
      }
    }
  };
  auto COMPUTE = [&](int kt, int buf) {
    const _Float16* B = Bb + (size_t)buf * NSLOT * 8;
    __builtin_amdgcn_s_setprio(1);
#pragma unroll
    for (int ks = 0; ks < 2; ++ks) {
      int seg = ks * 2 + (lane >> 5);
      half8 bh[3], bl[3];
#pragma unroll
      for (int nf = 0; nf < 3; ++nf) {
        int rr = (lane & 31) + nf * 32;
        bh[nf] = *(const half8*)(B + rr * 64 + (((0 + seg) ^ (rr & 7)) * 8));
        bl[nf] = *(const half8*)(B + rr * 64 + (((4 + seg) ^ (rr & 7)) * 8));
      }
#pragma unroll
      for (int mti = 0; mti < MT; ++mti) {
        int mt = w * MT + mti;
        int fid = ((mt * KT + kt) * 2 + ks) * 2;
        half8 ah = *(const half8*)(Wf + ((size_t)fid * 64 + lane) * 8);
        half8 al = *(const half8*)(Wf + ((size_t)(fid + 1) * 64 + lane) * 8);
#pragma unroll
        for (int nf = 0; nf < 3; ++nf) {
          acc[mti][nf] = __builtin_amdgcn_mfma_f32_32x32x16_f16(ah, bh[nf], acc[mti][nf], 0, 0, 0);
          acc[mti][nf] = __builtin_amdgcn_mfma_f32_32x32x16_f16(ah, bl[nf], acc[mti][nf], 0, 0, 0);
          acc[mti][nf] = __builtin_amdgcn_mfma_f32_32x32x16_f16(al, bh[nf], acc[mti][nf], 0, 0, 0);
        }
      }
    }
    __builtin_amdgcn_s_setprio(0);
  };

  ISSUE(0, 0);
  int cur = 0;
  for (int kt = 0; kt < KT; ++kt) {
    __builtin_amdgcn_sched_barrier(0);
    if (kt + 1 < KT) ISSUE(kt + 1, cur ^ 1);
    __builtin_amdgcn_sched_barrier(0);
    if (kt + 1 < KT) {
      // waves 0-3 just issued 2 loads, waves 4-7 issued 1 -> leave only those in flight
      if (w < 4) asm volatile("s_waitcnt vmcnt(2)" ::: "memory");
      else       asm volatile("s_waitcnt vmcnt(1)" ::: "memory");
    } else {
      asm volatile("s_waitcnt vmcnt(0)" ::: "memory");
    }
    __builtin_amdgcn_sched_barrier(0);
    __builtin_amdgcn_s_barrier();
    __builtin_amdgcn_sched_barrier(0);
    COMPUTE(kt, cur);
    asm volatile("s_waitcnt lgkmcnt(0)" ::: "memory");
    __builtin_amdgcn_sched_barrier(0);
    __builtin_amdgcn_s_barrier();
    cur ^= 1;
  }

  constexpr int SUBS = 512 / COUT;     // L1: 4, L2: 8
  constexpr int WR = 24 / SUBS;        // L1: 6, L2: 3
  int c = tid & (COUT - 1);
  int w0 = (tid / COUT) * WR;
  float s1 = BN_INV * g1[c], o1 = b1[c];
  float gv0 = gb[c], gv1 = gb[COUT + c], gv2 = gb[2 * COUT + c];

  for (int tr = 0; tr < 4; ++tr) {
    __syncthreads();
#pragma unroll
    for (int mti = 0; mti < MT; ++mti) {
#pragma unroll
      for (int nf = 0; nf < 3; ++nf) {
        int nloc = nf * 32 + (lane & 31) - tr * 24;
        if (nloc >= 0 && nloc < 24) {
          int mb_ = (w * MT + mti) * 32 + 4 * (lane >> 5);
#pragma unroll
          for (int r = 0; r < 16; ++r)
            ZL[(mb_ + (r & 3) + 8 * (r >> 2)) * 25 + nloc] = acc[mti][nf][r];
        }
      }
    }
    __syncthreads();
    float y[WR];
#pragma unroll
    for (int j = 0; j < WR; ++j) y[j] = 0.f;
#pragma unroll
    for (int k = 0; k < 3; ++k) {
#pragma unroll
      for (int v = 0; v < 24; ++v) {
        float zr = ZL[(k * COUT + c) * 25 + v];
        const float* ap = &AL[k * 576 + v * 24 + w0];
#pragma unroll
        for (int j = 0; j < WR; ++j) y[j] += zr * ap[j];
      }
    }
#pragma unroll
    for (int j = 0; j < WR; ++j) {
      int ww = w0 + j;
      float bias = gv0 * csL[ww] + gv1 * csL[24 + ww] + gv2 * csL[48 + ww];
      float yv = fmaxf((y[j] + bias) * s1 + o1, 0.f);
      _Float16 h = (_Float16)yv;
      YST[ww * COUT + c] = h;
      YST[24 * COUT + ww * COUT + c] = (_Float16)(yv - (float)h);
    }
    __syncthreads();
    // bulk 16B plane writes (slab contiguous in global) + float4 res writes
    constexpr int QT = 24 * COUT / 8;        // half8 per plane
    size_t nbase = (size_t)n0 + tr * 24;
    for (int idx = tid; idx < 2 * QT; idx += 512) {
      int plane = idx / QT, q = idx - plane * QT;
      _Float16* dst = (plane ? oL : oH) + nbase * COUT + q * 8;
      *(half8*)dst = *(half8*)(YST + plane * 24 * COUT + q * 8);
    }
    for (int idx = tid; idx < COUT * 6; idx += 512) {
      int cc = idx / 6, q = idx - cc * 6;
      float4 v4;
      v4.x = ZL[(M3 + cc) * 25 + 4 * q + 0];
      v4.y = ZL[(M3 + cc) * 25 + 4 * q + 1];
      v4.z = ZL[(M3 + cc) * 25 + 4 * q + 2];
      v4.w = ZL[(M3 + cc) * 25 + 4 * q + 3];
      *(float4*)(res_out + (size_t)cc * NBc + nbase + 4 * q) = v4;
    }
  }
}

// ============================= temporal conv (MFMA, 512 threads / 8 waves) =============================
// Block covers full M=CIO; waves tile (wm,wn) over M x 128-col N. Counted-vmcnt dbuf.
// FUSE_FC: apply fc to post-relu h in-register, reduce, write d_out directly.
template <int CIO, int MF, bool FUSE_FC>
__global__ __launch_bounds__(512) void k_tcn_mfma(
    const _Float16* __restrict__ yH, const _Float16* __restrict__ yL, // [NBc][CIO]
    const _Float16* __restrict__ Apack,
    const float* __restrict__ tb, const float* __restrict__ g2, const float* __restrict__ b2,
    const float* __restrict__ Zres,   // res rows [CIO][NBc] raw, or nullptr
    const float* __restrict__ rb, const float* __restrict__ rg, const float* __restrict__ rbb,
    _Float16* __restrict__ oH, _Float16* __restrict__ oL,  // [NBc][CIO] (unused if FUSE_FC)
    const float* __restrict__ fw, const float* __restrict__ fb,  // fc params (FUSE_FC)
    float* __restrict__ outp, int b0,
    int NBc)
{
  constexpr int KT = CIO / 32;
  constexpr int M = CIO;
  constexpr int NWAVE_M = M / (MF * 32);      // 256/MF2:4  128/MF1:4  64/MF1:2
  constexpr int NWAVE_N = 8 / NWAVE_M;        // 256:2  128:2  64:4
  constexpr int NF = 128 / (32 * NWAVE_N);    // 256:2  128:2  64:1
  constexpr int NROW = 224;                   // 128 cols + 96 halo rows
  __shared__ _Float16 Bt[2][NROW * 64];       // 2 x 28672 B
  __shared__ float scL[CIO], ofL[CIO], tbL[CIO], rscL[CIO], rofL[CIO], rbvL[CIO];
  __shared__ float fwL[FUSE_FC ? 384 : 4];
  int bx = blockIdx.x, bl = blockIdx.z;
  int tid = threadIdx.x, w = tid >> 6, lane = tid & 63;
  int wn = w % NWAVE_N, wm = w / NWAVE_N;
  int n0 = bx * 128;
  bool interior = (bx > 0) && (bx < 47);

  for (int i = tid; i < CIO; i += 512) {
    scL[i] = BN_INV * g2[i]; ofL[i] = b2[i]; tbL[i] = tb[i];
    if (Zres) { rscL[i] = BN_INV * rg[i]; rofL[i] = rbb[i]; rbvL[i] = rb[i]; }
  }
  if (FUSE_FC) { for (int i = tid; i < 384; i += 512) fwL[i] = fw[i]; }

  floatx16 acc[MF][NF] = {};
  const _Float16* ybH = yH + (size_t)bl * gN * CIO;
  const _Float16* ybL = yL + (size_t)bl * gN * CIO;
  int mt_base = wm * MF;

  auto ISSUE = [&](int kt, int buf) {   // async gload_lds; slots w*4+it, 28 used
#pragma unroll
    for (int it = 0; it < 4; ++it) {
      int slot = w * 4 + it;
      if (slot < 28) {
        int T = slot * 64 + lane;
        int r = T >> 3, s = T & 7;
        int sl = s ^ (r & 7);
        int pl = sl >> 2, seg = sl & 3;
        int n = n0 - 48 + r;
        const _Float16* src = (pl ? ybL : ybH) + (size_t)n * CIO + kt * 32 + seg * 8;
        GLOAD_LDS16(src, &Bt[buf][(size_t)slot * 512]);
      }
    }
  };
  auto ISSUE_EDGE = [&](int kt, int buf) {  // reg-staged, zero-filled halo
#pragma unroll
    for (int it = 0; it < 4; ++it) {
      int slot = w * 4 + it;
      if (slot < 28) {
        int T = slot * 64 + lane;
        int r = T >> 3, s = T & 7;
        int sl = s ^ (r & 7);
        int pl = sl >> 2, seg = sl & 3;
        int n = n0 - 48 + r;
        uint4 vv = make_uint4(0u, 0u, 0u, 0u);
        if (n >= 0 && n < gN)
          vv = *(const uint4*)((pl ? ybL : ybH) + (size_t)n * CIO + kt * 32 + seg * 8);
        *(uint4*)(&Bt[buf][(size_t)T * 8]) = vv;
      }
    }
  };
  auto COMPUTE = [&](int kt, int buf) {
    const _Float16* B = &Bt[buf][0];
    __builtin_amdgcn_s_setprio(1);
#pragma unroll
    for (int dt = 0; dt < 5; ++dt) {
#pragma unroll
      for (int ks = 0; ks < 2; ++ks) {
        int seg = ks * 2 + (lane >> 5);
        half8 bh[NF], blv[NF];
#pragma unroll
        for (int nf = 0; nf < NF; ++nf) {
          int rr = wn * (NF * 32) + nf * 32 + dt * 24 + (lane & 31);
          bh[nf]  = *(const half8*)(B + rr * 64 + (((0 + seg) ^ (rr & 7)) * 8));
          blv[nf] = *(const half8*)(B + rr * 64 + (((4 + seg) ^ (rr & 7)) * 8));
        }
#pragma unroll
        for (int mf = 0; mf < MF; ++mf) {
          int fid = ((((mt_base + mf) * KT + kt) * 2 + ks) * 5 + dt) * 2;
          half8 ah = *(const half8*)(Apack + ((size_t)fid * 64 + lane) * 8);
          half8 al = *(const half8*)(Apack + ((size_t)(fid + 1) * 64 + lane) * 8);
#pragma unroll
          for (int nf = 0; nf < NF; ++nf) {
            acc[mf][nf] = __builtin_amdgcn_mfma_f32_32x32x16_f16(ah, bh[nf], acc[mf][nf], 0, 0, 0);
            acc[mf][nf] = __builtin_amdgcn_mfma_f32_32x32x16_f16(ah, blv[nf], acc[mf][nf], 0, 0, 0);
            acc[mf][nf] = __builtin_amdgcn_mfma_f32_32x32x16_f16(al, bh[nf], acc[mf][nf], 0, 0, 0);
          }
        }
      }
    }
    __builtin_amdgcn_s_setprio(0);
  };

  if (interior) {
    ISSUE(0, 0);
    int cur = 0;
    for (int kt = 0; kt < KT; ++kt) {
      __builtin_amdgcn_sched_barrier(0);
      if (kt + 1 < KT) ISSUE(kt + 1, cur ^ 1);
      __builtin_amdgcn_sched_barrier(0);
      if (kt + 1 < KT) asm volatile("s_waitcnt vmcnt(4)" ::: "memory");
      else             asm volatile("s_waitcnt vmcnt(0)" ::: "memory");
      __builtin_amdgcn_sched_barrier(0);
      __builtin_amdgcn_s_barrier();
      __builtin_amdgcn_sched_barrier(0);
      COMPUTE(kt, cur);
      asm volatile("s_waitcnt lgkmcnt(0)" ::: "memory");
      __builtin_amdgcn_sched_barrier(0);
      __builtin_amdgcn_s_barrier();
      cur ^= 1;
    }
  } else {
    for (int kt = 0; kt < KT; ++kt) {
      __syncthreads();
      ISSUE_EDGE(kt, 0);
      __syncthreads();
      COMPUTE(kt, 0);
    }
  }

  // epilogue: acc -> z (bias + bn2 + res + relu), in place
  int blgN = bl * gN;
#pragma unroll
  for (int mf = 0; mf < MF; ++mf) {
    int m32 = wm * MF * 32 + mf * 32 + 4 * (lane >> 5);
#pragma unroll
    for (int nf = 0; nf < NF; ++nf) {
      int n = n0 + wn * (NF * 32) + nf * 32 + (lane & 31);
      size_t nflat = (size_t)blgN + n;
#pragma unroll
      for (int r = 0; r < 16; ++r) {
        int co = m32 + (r & 3) + 8 * (r >> 2);
        float z = (acc[mf][nf][r] + tbL[co]) * scL[co] + ofL[co];
        if (Zres) z += (Zres[(size_t)co * NBc + nflat] + rbvL[co]) * rscL[co] + rofL[co];
        acc[mf][nf][r] = fmaxf(z, 0.f);
      }
    }
  }

  if constexpr (FUSE_FC) {
    // MF=1, NF=1, NWAVE_M=2 (wm 0..1), NWAVE_N=4 (wn 0..3).
    __syncthreads();                   // Bt free
    float* FC = (float*)&Bt[0][0];     // [2 wm][128 n][6]
    float p[6];
#pragma unroll
    for (int o = 0; o < 6; ++o) p[o] = 0.f;
    int m32 = wm * 32 + 4 * (lane >> 5);
#pragma unroll
    for (int r = 0; r < 16; ++r) {
      int co = m32 + (r & 3) + 8 * (r >> 2);
      float z = acc[0][0][r];
#pragma unroll
      for (int o = 0; o < 6; ++o) p[o] += fwL[o * 64 + co] * z;
    }
#pragma unroll
    for (int o = 0; o < 6; ++o) p[o] += __shfl_xor(p[o], 32);
    if (lane < 32) {
      int nloc = wn * 32 + lane;
#pragma unroll
      for (int o = 0; o < 6; ++o)
        FC[(wm * 128 + nloc) * 6 + o] = p[o];
    }
    __syncthreads();
    for (int idx = tid; idx < 768; idx += 512) {
      int nloc = idx / 6, o = idx % 6;
      float val = fb[o] + FC[nloc * 6 + o] + FC[(128 + nloc) * 6 + o];
      int n = n0 + nloc;
      int t = n / 24, v = n % 24;
      outp[(((size_t)(b0 + bl) * gT + t) * gV + v) * 6 + o] = val;
    }
  } else {
    // LDS-transpose + 16B plane writes.  ST rows per pass chosen to fit Bt.
    constexpr int CPB = CIO / 2;       // co-pair dwords per n-row
    constexpr int NHALF = (128 * (CPB + 1) * 4 > 2 * NROW * 64 * 2) ? 2 : 1;
    constexpr int ROWS_P = 128 / NHALF;
    constexpr int PITCH = CPB + 1;
    uint* ST = (uint*)&Bt[0][0];
    uint* oH32 = (uint*)oH;
    uint* oL32 = (uint*)oL;
    constexpr int QITERS = ROWS_P * CPB / 4 / 512;

#pragma unroll
    for (int half = 0; half < NHALF; ++half) {
#pragma unroll
      for (int pass = 0; pass < 2; ++pass) {
        __syncthreads();
        if (NHALF == 1 || wn == half) {
          int cl = wm * MF * 32;
#pragma unroll
          for (int mf = 0; mf < MF; ++mf) {
#pragma unroll
            for (int nf = 0; nf < NF; ++nf) {
              int nl = wn * (NF * 32) + nf * 32 + (lane & 31) - half * ROWS_P;
#pragma unroll
              for (int r = 0; r < 16; r += 2) {
                float z0 = acc[mf][nf][r], z1 = acc[mf][nf][r + 1];
                _Float16 a0 = (_Float16)z0, a1 = (_Float16)z1;
                if (pass == 1) { a0 = (_Float16)(z0 - (float)a0); a1 = (_Float16)(z1 - (float)a1); }
                half2v p2; p2[0] = a0; p2[1] = a1;
                int col2 = (cl + mf * 32 + 4 * (lane >> 5) + (r & 3) + 8 * (r >> 2)) >> 1;
                ST[nl * PITCH + col2] = *(uint*)&p2;
              }
            }
          }
        }
        __syncthreads();
        uint* dst = (pass == 0) ? oH32 : oL32;
#pragma unroll
        for (int i = 0; i < QITERS; ++i) {
          int idx = i * 512 + tid;                    // quad id
          int row = idx / (CPB / 4), c4 = (idx % (CPB / 4)) * 4;
          uint4 v;
          v.x = ST[row * PITCH + c4 + 0];
          v.y = ST[row * PITCH + c4 + 1];
          v.z = ST[row * PITCH + c4 + 2];
          v.w = ST[row * PITCH + c4 + 3];
          *(uint4*)(dst + ((size_t)blgN + n0 + half * ROWS_P + row) * (CIO / 2) + c4) = v;
        }
      }
    }
  }
}

// ============================= host =============================
extern "C" void kernel_launch(void* const* d_in, const int* in_sizes, int n_in,
                              void* d_out, int out_size, void* d_ws, size_t ws_size,
                              hipStream_t stream) {
  const float* x    = (const float*)d_in[0];
  const float* A    = (const float*)d_in[1];
  const float* dbg  = (const float*)d_in[2];
  const float* dbb  = (const float*)d_in[3];
  const float* ei0  = (const float*)d_in[4];
  const float* ei1  = (const float*)d_in[5];
  const float* ei2  = (const float*)d_in[6];
  const float* w0g  = (const float*)d_in[7];
  const float* gb0  = (const float*)d_in[8];
  const float* g10  = (const float*)d_in[9];
  const float* b10  = (const float*)d_in[10];
  const float* tw0  = (const float*)d_in[11];
  const float* tb0  = (const float*)d_in[12];
  const float* g20  = (const float*)d_in[13];
  const float* b20  = (const float*)d_in[14];
  const float* w1g  = (const float*)d_in[15];
  const float* gb1  = (const float*)d_in[16];
  const float* g11  = (const float*)d_in[17];
  const float* b11  = (const float*)d_in[18];
  const float* tw1  = (const float*)d_in[19];
  const float* tb1  = (const float*)d_in[20];
  const float* g21  = (const float*)d_in[21];
  const float* b21  = (const float*)d_in[22];
  const float* rw1  = (const float*)d_in[23];
  const float* rb1  = (const float*)d_in[24];
  const float* rg1  = (const float*)d_in[25];
  const float* rbb1 = (const float*)d_in[26];
  const float* w2g  = (const float*)d_in[27];
  const float* gb2  = (const float*)d_in[28];
  const float* g12  = (const float*)d_in[29];
  const float* b12  = (const float*)d_in[30];
  const float* tw2  = (const float*)d_in[31];
  const float* tb2  = (const float*)d_in[32];
  const float* g22  = (const float*)d_in[33];
  const float* b22  = (const float*)d_in[34];
  const float* rw2  = (const float*)d_in[35];
  const float* rb2  = (const float*)d_in[36];
  const float* rg2  = (const float*)d_in[37];
  const float* rbb2 = (const float*)d_in[38];
  const float* fw   = (const float*)d_in[39];
  const float* fb   = (const float*)d_in[40];
  float* outp = (float*)d_out;
  float* ws = (float*)d_ws;

  // ws layout (floats)
  size_t off = 0;
  auto alloc = [&](size_t n) { size_t o = off; off += n; return o; };
  size_t oAE  = alloc(3 * 1728);
  size_t oCS  = alloc(3 * 72);
  size_t oA0  = alloc((size_t)1280 * 512 / 2);  // tcn0 frags
  size_t oA1  = alloc((size_t)320 * 512 / 2);
  size_t oA2  = alloc((size_t)80 * 512 / 2);
  size_t oWz1 = alloc((size_t)512 * 512 / 2);   // 512 frags * 512 halves
  size_t oWz2 = alloc((size_t)128 * 512 / 2);
  off = (off + 3) & ~(size_t)3;

  // per batch (floats/n): planes buf1 256 + planes buf2 256 + res rows 128 = 640
  const size_t perBatchBytes = (size_t)gN * 640 * 4;   // 15.73 MB
  int Bc = 32;
  while (Bc > 1 && off * 4 + (size_t)Bc * perBatchBytes > ws_size) Bc >>= 1;
  int NBc = Bc * gN;

  float* B1 = ws + off;
  float* B2 = B1 + (size_t)NBc * 256;
  float* Rb = B2 + (size_t)NBc * 256;          // res rows [<=128][NBc]
  _Float16* b1h = (_Float16*)B1;
  _Float16* b2h = (_Float16*)B2;
  _Float16* A0 = (_Float16*)(ws + oA0);
  _Float16* A1 = (_Float16*)(ws + oA1);
  _Float16* A2 = (_Float16*)(ws + oA2);
  _Float16* Wz1 = (_Float16*)(ws + oWz1);
  _Float16* Wz2 = (_Float16*)(ws + oWz2);

  // ---- prep ----
  k_prep_aeff<<<21, 256, 0, stream>>>(A, ei0, ei1, ei2, ws + oAE, ws + oCS);
  k_prep_twf<<<320, 256, 0, stream>>>(tw0, A0, 256, 8);
  k_prep_twf<<<80, 256, 0, stream>>>(tw1, A1, 128, 4);
  k_prep_twf<<<20, 256, 0, stream>>>(tw2, A2, 64, 2);
  k_pack_wz<<<128, 256, 0, stream>>>(w1g, rw1, Wz1, 256, 8, 384);  // M=512,K=256
  k_pack_wz<<<32, 256, 0, stream>>>(w2g, rw2, Wz2, 128, 4, 192);   // M=256,K=128

  for (int b0 = 0; b0 < 32; b0 += Bc) {
    // layer 0: gcn0 -> P1(256); tcn0 -> P2(256)
    k_gcn0<<<dim3(gT / 4, Bc), 256, 0, stream>>>(x, ws + oAE, ws + oCS, dbg, dbb,
                                                 w0g, gb0, g10, b10,
                                                 b1h, b1h + (size_t)NBc * 256, b0);
    k_tcn_mfma<256, 2, false><<<dim3(48, 1, Bc), 512, 0, stream>>>(
        b1h, b1h + (size_t)NBc * 256, A0, tb0, g20, b20,
        nullptr, nullptr, nullptr, nullptr,
        b2h, b2h + (size_t)NBc * 256, nullptr, nullptr, nullptr, 0, NBc);
    // layer 1: fused gcn (P2 -> P1 planes + res rows); tcn1(P1 + res) -> P2
    k_gcnfuse<256, 128><<<dim3(NBc / 96), 512, 0, stream>>>(
        b2h, b2h + (size_t)NBc * 256, Wz1,
        ws + oAE + 1728, ws + oCS + 72, gb1, g11, b11,
        b1h, b1h + (size_t)NBc * 128, Rb, NBc);
    k_tcn_mfma<128, 1, false><<<dim3(48, 1, Bc), 512, 0, stream>>>(
        b1h, b1h + (size_t)NBc * 128, A1, tb1, g21, b21,
        Rb, rb1, rg1, rbb1,
        b2h, b2h + (size_t)NBc * 128, nullptr, nullptr, nullptr, 0, NBc);
    // layer 2
    k_gcnfuse<128, 64><<<dim3(NBc / 96), 512, 0, stream>>>(
        b2h, b2h + (size_t)NBc * 128, Wz2,
        ws + oAE + 2 * 1728, ws + oCS + 144, gb2, g12, b12,
        b1h, b1h + (size_t)NBc * 64, Rb, NBc);
    // tcn2 + fused fc -> d_out directly
    k_tcn_mfma<64, 1, true><<<dim3(48, 1, Bc), 512, 0, stream>>>(
        b1h, b1h + (size_t)NBc * 64, A2, tb2, g22, b22,
        Rb, rb2, rg2, rbb2,
        nullptr, nullptr, fw, fb, outp, b0, NBc);
  }
  (void)in_sizes; (void)n_in; (void)out_size;
}